// Round 1
// baseline (7628.403 us; speedup 1.0000x reference)
//
#include <hip/hip_runtime.h>
#include <hip/hip_bf16.h>

#define BB 16
#define NN 196
#define CC 2048
#define C8 256
#define HH 4
#define DM 512
#define FF (CC*NN)   // 401408

// ---------------------------------------------------------------- k_diff
__global__ __launch_bounds__(256) void k_diff(const float* __restrict__ bef,
                                              const float* __restrict__ aft,
                                              float* __restrict__ dif)
{
    const float inv3 = 1.0f / 3.0f;
    const size_t n4 = (size_t)BB * NN * CC / 4;
    for (size_t i = (size_t)blockIdx.x * blockDim.x + threadIdx.x; i < n4;
         i += (size_t)gridDim.x * blockDim.x) {
        float4 a = ((const float4*)aft)[i];
        float4 b = ((const float4*)bef)[i];
        float4 d;
        d.x = (a.x - b.x) * inv3; d.y = (a.y - b.y) * inv3;
        d.z = (a.z - b.z) * inv3; d.w = (a.w - b.w) * inv3;
        ((float4*)dif)[i] = d;
    }
}

// ---------------------------------------------------------------- k_qk
// z=0: Q[h,b,n,o] = sum_c Wq[h,o,c]*(bef+h*dif)[b,n,c] + bq[h,o]
// z=1: K[h,b,m,o] = h * (sum_c Wk[h,o,c]*dif[b,m,c]) + bk[h,o]
__global__ __launch_bounds__(256) void k_qk(
    const float* __restrict__ bef, const float* __restrict__ dif,
    const float* __restrict__ Wq, const float* __restrict__ bq,
    const float* __restrict__ Wk, const float* __restrict__ bk,
    float* __restrict__ Qs, float* __restrict__ Ks)
{
    __shared__ float As[64][17];
    __shared__ float Bs[64][17];
    const int t  = threadIdx.x;
    const int mt = blockIdx.x >> 2, nt = blockIdx.x & 3;
    const int h  = blockIdx.y >> 4, b  = blockIdx.y & 15;
    const int isK = blockIdx.z;
    const float fh = (float)h;
    const int lr = t >> 2;
    const int lk = (t & 3) << 2;
    const int gm = mt * 64 + lr;      // row (n / m), may be >=196
    const int go = nt * 64 + lr;      // col (o), always <256
    const float* W = (isK ? Wk : Wq) + (size_t)h * C8 * CC;
    const float* Arow = bef + ((size_t)b * NN + gm) * CC + lk;
    const float* Drow = dif + ((size_t)b * NN + gm) * CC + lk;
    const float* Brow = W + (size_t)go * CC + lk;
    const int tr = t >> 4, tc = t & 15;
    float acc[4][4] = {{0.f}};

    for (int k0 = 0; k0 < CC; k0 += 16) {
        float4 av = make_float4(0.f, 0.f, 0.f, 0.f);
        if (gm < NN) {
            if (isK) {
                av = *(const float4*)(Drow + k0);
            } else {
                float4 xv = *(const float4*)(Arow + k0);
                float4 dv = *(const float4*)(Drow + k0);
                av.x = xv.x + fh * dv.x; av.y = xv.y + fh * dv.y;
                av.z = xv.z + fh * dv.z; av.w = xv.w + fh * dv.w;
            }
        }
        float4 wv = *(const float4*)(Brow + k0);
        As[lr][lk + 0] = av.x; As[lr][lk + 1] = av.y;
        As[lr][lk + 2] = av.z; As[lr][lk + 3] = av.w;
        Bs[lr][lk + 0] = wv.x; Bs[lr][lk + 1] = wv.y;
        Bs[lr][lk + 2] = wv.z; Bs[lr][lk + 3] = wv.w;
        __syncthreads();
#pragma unroll
        for (int kk = 0; kk < 16; ++kk) {
            float a[4], bb[4];
#pragma unroll
            for (int i = 0; i < 4; ++i) a[i] = As[tr * 4 + i][kk];
#pragma unroll
            for (int j = 0; j < 4; ++j) bb[j] = Bs[tc * 4 + j][kk];
#pragma unroll
            for (int i = 0; i < 4; ++i)
#pragma unroll
                for (int j = 0; j < 4; ++j)
                    acc[i][j] = fmaf(a[i], bb[j], acc[i][j]);
        }
        __syncthreads();
    }

    float* Out = isK ? Ks : Qs;
    const float* bias = isK ? bk : bq;
    const size_t obase = (size_t)(h * BB + b) * NN * C8;
#pragma unroll
    for (int i = 0; i < 4; ++i) {
        int m = mt * 64 + tr * 4 + i;
        if (m < NN) {
#pragma unroll
            for (int j = 0; j < 4; ++j) {
                int o = nt * 64 + tc * 4 + j;
                float v = isK ? (fh * acc[i][j] + bias[h * C8 + o])
                              : (acc[i][j] + bias[h * C8 + o]);
                Out[obase + (size_t)m * C8 + o] = v;
            }
        }
    }
}

// ---------------------------------------------------------------- k_energy
// E[hb,n,m] = sum_o Q[hb,n,o]*K[hb,m,o]
__global__ __launch_bounds__(256) void k_energy(
    const float* __restrict__ Qs, const float* __restrict__ Ks,
    float* __restrict__ E)
{
    __shared__ float As[64][17];
    __shared__ float Bs[64][17];
    const int t  = threadIdx.x;
    const int mt = blockIdx.x >> 2, nt = blockIdx.x & 3;
    const int hb = blockIdx.y;
    const int lr = t >> 2, lk = (t & 3) << 2;
    const int gn = mt * 64 + lr, gm = nt * 64 + lr;
    const float* Qrow = Qs + ((size_t)hb * NN + gn) * C8 + lk;
    const float* Krow = Ks + ((size_t)hb * NN + gm) * C8 + lk;
    const int tr = t >> 4, tc = t & 15;
    float acc[4][4] = {{0.f}};

    for (int k0 = 0; k0 < C8; k0 += 16) {
        float4 qv = make_float4(0.f, 0.f, 0.f, 0.f);
        float4 kv = make_float4(0.f, 0.f, 0.f, 0.f);
        if (gn < NN) qv = *(const float4*)(Qrow + k0);
        if (gm < NN) kv = *(const float4*)(Krow + k0);
        As[lr][lk + 0] = qv.x; As[lr][lk + 1] = qv.y;
        As[lr][lk + 2] = qv.z; As[lr][lk + 3] = qv.w;
        Bs[lr][lk + 0] = kv.x; Bs[lr][lk + 1] = kv.y;
        Bs[lr][lk + 2] = kv.z; Bs[lr][lk + 3] = kv.w;
        __syncthreads();
#pragma unroll
        for (int kk = 0; kk < 16; ++kk) {
            float a[4], bb[4];
#pragma unroll
            for (int i = 0; i < 4; ++i) a[i] = As[tr * 4 + i][kk];
#pragma unroll
            for (int j = 0; j < 4; ++j) bb[j] = Bs[tc * 4 + j][kk];
#pragma unroll
            for (int i = 0; i < 4; ++i)
#pragma unroll
                for (int j = 0; j < 4; ++j)
                    acc[i][j] = fmaf(a[i], bb[j], acc[i][j]);
        }
        __syncthreads();
    }
#pragma unroll
    for (int i = 0; i < 4; ++i) {
        int n = mt * 64 + tr * 4 + i;
        if (n < NN) {
#pragma unroll
            for (int j = 0; j < 4; ++j) {
                int m = nt * 64 + tc * 4 + j;
                if (m < NN)
                    E[(size_t)hb * NN * NN + (size_t)n * NN + m] = acc[i][j];
            }
        }
    }
}

// ---------------------------------------------------------------- k_softmax
// row-softmax over m; writes attn straight into alphas (B,1,N,N,H) layout
__global__ __launch_bounds__(64) void k_softmax(const float* __restrict__ E,
                                                float* __restrict__ alphas)
{
    const int r = blockIdx.x;                 // (h*BB+b)*NN + n
    const int t = threadIdx.x;
    const int hb = r / NN, n = r % NN;
    const int h = hb >> 4, b = hb & 15;
    const float* row = E + (size_t)r * NN;
    float v[4];
    float mx = -1e30f;
#pragma unroll
    for (int j = 0; j < 4; ++j) {
        int m = t + j * 64;
        v[j] = (m < NN) ? row[m] : -1e30f;
        mx = fmaxf(mx, v[j]);
    }
#pragma unroll
    for (int off = 32; off >= 1; off >>= 1) mx = fmaxf(mx, __shfl_xor(mx, off));
    float s = 0.f;
#pragma unroll
    for (int j = 0; j < 4; ++j) {
        int m = t + j * 64;
        if (m < NN) { v[j] = __expf(v[j] - mx); s += v[j]; }
    }
#pragma unroll
    for (int off = 32; off >= 1; off >>= 1) s += __shfl_xor(s, off);
    const float inv = 1.0f / s;
#pragma unroll
    for (int j = 0; j < 4; ++j) {
        int m = t + j * 64;
        if (m < NN)
            alphas[(((size_t)b * NN + n) * NN + m) * HH + h] = v[j] * inv;
    }
}

// ---------------------------------------------------------------- k_vpv
// Per (h,b,64-channel tile): V = Wv@x + bv (into LDS, bf16), then
// out = gamma * V@attn^T + x, written to outs[h][b][c][m].
__global__ __launch_bounds__(256) void k_vpv(
    const float* __restrict__ bef, const float* __restrict__ dif,
    const float* __restrict__ Wv, const float* __restrict__ bv,
    const float* __restrict__ gamma, const float* __restrict__ alphas,
    float* __restrict__ outs)
{
    __shared__ float fs[4432];              // phase1: As[64][17]+Bs[16][209]; phase2: Sa[208][17]
    __shared__ __hip_bfloat16 Vs[64 * 209]; // V tile, then x tile
    float* As = fs;
    float* Bs = fs + 64 * 17;
    float* Sa = fs;

    const int t  = threadIdx.x;
    const int ct = blockIdx.x;              // channel tile 0..31
    const int h  = blockIdx.y >> 4, b = blockIdx.y & 15;
    const float fh = (float)h;
    const int tr = t >> 4, tc = t & 15;
    const int lr = t >> 2, lk = (t & 3) << 2;
    const float* Wrow = Wv + ((size_t)(h * CC + ct * 64 + lr)) * CC + lk;

    float acc[4][13];
#pragma unroll
    for (int i = 0; i < 4; ++i)
#pragma unroll
        for (int j = 0; j < 13; ++j) acc[i][j] = 0.f;

    // ---- phase 1: V tile = Wv[h, ct*64..+64, :] @ x[b, :, :]^T
    for (int k0 = 0; k0 < CC; k0 += 16) {
        float4 wv = *(const float4*)(Wrow + k0);
        As[lr * 17 + lk + 0] = wv.x; As[lr * 17 + lk + 1] = wv.y;
        As[lr * 17 + lk + 2] = wv.z; As[lr * 17 + lk + 3] = wv.w;
#pragma unroll
        for (int j = 0; j < 13; ++j) {
            int idx = t + j * 256;
            if (idx < NN * 16) {
                int n = idx >> 4, kk = idx & 15;
                size_t g = ((size_t)b * NN + n) * CC + k0 + kk;
                Bs[kk * 209 + n] = bef[g] + fh * dif[g];
            }
        }
        if (t < 208) {                       // zero pad columns 196..208
            int kk2 = t / 13;
            int n2 = 196 + (t - kk2 * 13);
            Bs[kk2 * 209 + n2] = 0.f;
        }
        __syncthreads();
#pragma unroll
        for (int kk = 0; kk < 16; ++kk) {
            float a[4];
#pragma unroll
            for (int i = 0; i < 4; ++i) a[i] = As[(tr * 4 + i) * 17 + kk];
#pragma unroll
            for (int j = 0; j < 13; ++j) {
                float bb = Bs[kk * 209 + tc * 13 + j];
#pragma unroll
                for (int i = 0; i < 4; ++i)
                    acc[i][j] = fmaf(a[i], bb, acc[i][j]);
            }
        }
        __syncthreads();
    }
    // store V tile (+bias) to LDS as bf16
#pragma unroll
    for (int i = 0; i < 4; ++i) {
        float bvv = bv[h * CC + ct * 64 + tr * 4 + i];
#pragma unroll
        for (int j = 0; j < 13; ++j)
            Vs[(tr * 4 + i) * 209 + tc * 13 + j] = __float2bfloat16(acc[i][j] + bvv);
    }
    __syncthreads();

    // ---- phase 2: out[c,m] = sum_n V[c,n]*attn[m,n]
#pragma unroll
    for (int i = 0; i < 4; ++i)
#pragma unroll
        for (int j = 0; j < 13; ++j) acc[i][j] = 0.f;

    for (int ntile = 0; ntile < 13; ++ntile) {
        int n0 = ntile * 16;
#pragma unroll
        for (int j = 0; j < 13; ++j) {
            int idx = t + j * 256;           // covers 208*16 = 3328 exactly
            int m = idx >> 4, kk = idx & 15;
            int n = n0 + kk;
            float val = 0.f;
            if (m < NN && n < NN)
                val = alphas[(((size_t)b * NN + m) * NN + n) * HH + h];
            Sa[m * 17 + kk] = val;
        }
        __syncthreads();
#pragma unroll
        for (int kk = 0; kk < 16; ++kk) {
            float a[4];
#pragma unroll
            for (int i = 0; i < 4; ++i)
                a[i] = __bfloat162float(Vs[(tr * 4 + i) * 209 + n0 + kk]);
#pragma unroll
            for (int j = 0; j < 13; ++j) {
                float bb = Sa[(tc * 13 + j) * 17 + kk];
#pragma unroll
                for (int i = 0; i < 4; ++i)
                    acc[i][j] = fmaf(a[i], bb, acc[i][j]);
            }
        }
        __syncthreads();
    }

    // ---- epilogue: stage x tile (coalesced) into Vs, then out = gamma*acc + x
#pragma unroll
    for (int j = 0; j < 49; ++j) {
        int idx = t + j * 256;               // 49*256 = 12544 = 196*64 exactly
        int m = idx >> 6, cc = idx & 63;
        size_t g = ((size_t)b * NN + m) * CC + ct * 64 + cc;
        Vs[cc * 209 + m] = __float2bfloat16(bef[g] + fh * dif[g]);
    }
    __syncthreads();
    const float gam = gamma[h];
    const size_t ob = ((size_t)(h * BB + b) * CC + ct * 64) * NN;
#pragma unroll
    for (int i = 0; i < 4; ++i) {
        int cc = tr * 4 + i;
#pragma unroll
        for (int j = 0; j < 13; ++j) {
            int m = tc * 13 + j;
            if (m < NN)
                outs[ob + (size_t)cc * NN + m] =
                    gam * acc[i][j] + __bfloat162float(Vs[cc * 209 + m]);
        }
    }
}

// ---------------------------------------------------------------- k_lin
// split-K GEMM: part[ch, a, dm] = sum_{k in chunk ch} outs[row(a), k] * Wl[dm, k]
__global__ __launch_bounds__(256) void k_lin(
    const float* __restrict__ outs, const float* __restrict__ Wl,
    float* __restrict__ part)
{
    __shared__ float As[64][17];
    __shared__ float Bs[64][17];
    const int t  = threadIdx.x;
    const int dt = blockIdx.x;               // dm tile 0..7
    const int ch = blockIdx.y;               // k chunk 0..63 (6272 each)
    const int lr = t >> 2, lk = (t & 3) << 2;
    const int aRow = lr;                     // a = b*H + h
    const int b_ = aRow >> 2, h_ = aRow & 3;
    const float* Arow = outs + (size_t)(h_ * BB + b_) * FF + (size_t)ch * 6272 + lk;
    const float* Brow = Wl + (size_t)(dt * 64 + lr) * FF + (size_t)ch * 6272 + lk;
    const int tr = t >> 4, tc = t & 15;
    float acc[4][4] = {{0.f}};

    for (int k0 = 0; k0 < 6272; k0 += 16) {
        float4 av = *(const float4*)(Arow + k0);
        float4 bv = *(const float4*)(Brow + k0);
        As[lr][lk + 0] = av.x; As[lr][lk + 1] = av.y;
        As[lr][lk + 2] = av.z; As[lr][lk + 3] = av.w;
        Bs[lr][lk + 0] = bv.x; Bs[lr][lk + 1] = bv.y;
        Bs[lr][lk + 2] = bv.z; Bs[lr][lk + 3] = bv.w;
        __syncthreads();
#pragma unroll
        for (int kk = 0; kk < 16; ++kk) {
            float a[4], bb[4];
#pragma unroll
            for (int i = 0; i < 4; ++i) a[i] = As[tr * 4 + i][kk];
#pragma unroll
            for (int j = 0; j < 4; ++j) bb[j] = Bs[tc * 4 + j][kk];
#pragma unroll
            for (int i = 0; i < 4; ++i)
#pragma unroll
                for (int j = 0; j < 4; ++j)
                    acc[i][j] = fmaf(a[i], bb[j], acc[i][j]);
        }
        __syncthreads();
    }
#pragma unroll
    for (int i = 0; i < 4; ++i)
#pragma unroll
        for (int j = 0; j < 4; ++j)
            part[((size_t)ch * 64 + tr * 4 + i) * DM + dt * 64 + tc * 4 + j] = acc[i][j];
}

// ---------------------------------------------------------------- k_red
__global__ __launch_bounds__(256) void k_red(const float* __restrict__ part,
                                             const float* __restrict__ bl,
                                             float* __restrict__ out0)
{
    int gid = blockIdx.x * 256 + threadIdx.x;
    if (gid < 64 * DM) {
        int dm = gid & (DM - 1);
        float s = bl[dm];
        for (int c2 = 0; c2 < 64; ++c2) s += part[(size_t)c2 * 64 * DM + gid];
        out0[gid] = s;
    }
}

// ---------------------------------------------------------------- launch
extern "C" void kernel_launch(void* const* d_in, const int* in_sizes, int n_in,
                              void* d_out, int out_size, void* d_ws, size_t ws_size,
                              hipStream_t stream)
{
    const float* bef   = (const float*)d_in[0];
    const float* aft   = (const float*)d_in[1];
    const float* Wq    = (const float*)d_in[2];
    const float* bq    = (const float*)d_in[3];
    const float* Wk    = (const float*)d_in[4];
    const float* bk    = (const float*)d_in[5];
    const float* Wv    = (const float*)d_in[6];
    const float* bv    = (const float*)d_in[7];
    const float* gamma = (const float*)d_in[8];
    const float* Wl    = (const float*)d_in[9];
    const float* bl    = (const float*)d_in[10];

    float* out0   = (float*)d_out;
    float* alphas = out0 + (size_t)BB * HH * DM;   // 32768

    float* ws   = (float*)d_ws;
    float* diff = ws;                                   // 6,422,528
    float* Qs   = diff + (size_t)BB * NN * CC;          // 3,211,264
    float* Ks   = Qs + (size_t)HH * BB * NN * C8;       // 3,211,264
    float* E    = Ks + (size_t)HH * BB * NN * C8;       // 2,458,624
    float* outs = E + (size_t)HH * BB * NN * NN;        // 25,690,112
    float* part = outs + (size_t)HH * BB * CC * NN;     // 2,097,152
    // total ws: ~172.4 MB (fp32)

    k_diff<<<2048, 256, 0, stream>>>(bef, aft, diff);
    k_qk<<<dim3(16, 64, 2), 256, 0, stream>>>(bef, diff, Wq, bq, Wk, bk, Qs, Ks);
    k_energy<<<dim3(16, 64), 256, 0, stream>>>(Qs, Ks, E);
    k_softmax<<<HH * BB * NN, 64, 0, stream>>>(E, alphas);
    k_vpv<<<dim3(32, 64), 256, 0, stream>>>(bef, diff, Wv, bv, gamma, alphas, outs);
    k_lin<<<dim3(8, 64), 256, 0, stream>>>(outs, Wl, part);
    k_red<<<128, 256, 0, stream>>>(part, bl, out0);
}

// Round 2
// 1230.902 us; speedup vs baseline: 6.1974x; 6.1974x over previous
//
#include <hip/hip_runtime.h>
#include <hip/hip_bf16.h>

#define BB 16
#define NN 196
#define NP 224
#define CC 2048
#define C8 256
#define HH 4
#define DM 512
#define FF (CC*NN)   // 401408

typedef unsigned short u16;
typedef __attribute__((ext_vector_type(4))) u16 u16x4;
typedef __attribute__((ext_vector_type(8))) u16 u16x8;
typedef __attribute__((ext_vector_type(8))) short bf16x8;
typedef __attribute__((ext_vector_type(4))) float f32x4;

typedef __attribute__((address_space(1))) unsigned int as1_uint;
typedef __attribute__((address_space(3))) unsigned int as3_uint;

__device__ __forceinline__ void cp16(void* l, const void* g) {
    __builtin_amdgcn_global_load_lds((as1_uint*)g, (as3_uint*)l, 16, 0, 0);
}

__device__ __forceinline__ u16 f2bf(float f) {
    union { float f; unsigned u; } x; x.f = f;
    unsigned r = x.u + 0x7FFF + ((x.u >> 16) & 1);
    return (u16)(r >> 16);
}
__device__ __forceinline__ float bf2f(u16 u) {
    union { unsigned u; float f; } x; x.u = ((unsigned)u) << 16;
    return x.f;
}

// ---------------------------------------------------------------- k_prep
// dif = (aft-bef)/3 (fp32, for k_qk); xh[h][b][n][c] = bef + h*dif (bf16,
// rows n=196..223 zeroed)
__global__ __launch_bounds__(256) void k_prep(const float* __restrict__ bef,
                                              const float* __restrict__ aft,
                                              float* __restrict__ dif,
                                              u16* __restrict__ xh)
{
    const float inv3 = 1.0f / 3.0f;
    const size_t n4 = (size_t)BB * NN * CC / 4;
    const size_t stride = (size_t)gridDim.x * blockDim.x;
    for (size_t i = (size_t)blockIdx.x * blockDim.x + threadIdx.x; i < n4; i += stride) {
        float4 a = ((const float4*)aft)[i];
        float4 b = ((const float4*)bef)[i];
        float4 d;
        d.x = (a.x - b.x) * inv3; d.y = (a.y - b.y) * inv3;
        d.z = (a.z - b.z) * inv3; d.w = (a.w - b.w) * inv3;
        ((float4*)dif)[i] = d;
        size_t bn = i >> 9;                 // (i*4)/2048
        int c = (int)(i & 511) * 4;
        int b_ = (int)(bn / NN), n = (int)(bn % NN);
#pragma unroll
        for (int h = 0; h < HH; ++h) {
            float fh = (float)h;
            u16x4 u;
            u.x = f2bf(b.x + fh * d.x); u.y = f2bf(b.y + fh * d.y);
            u.z = f2bf(b.z + fh * d.z); u.w = f2bf(b.w + fh * d.w);
            *(u16x4*)(xh + ((size_t)(h * BB + b_) * NP + n) * CC + c) = u;
        }
    }
    // zero pad rows n=196..223: 4*16*28*2048 u16 = 917504 u16x4
    const size_t npad = (size_t)HH * BB * (NP - NN) * CC / 4;
    for (size_t i = (size_t)blockIdx.x * blockDim.x + threadIdx.x; i < npad; i += stride) {
        size_t hb = i / ((NP - NN) * CC / 4);
        size_t rem = i % ((NP - NN) * CC / 4);
        int pn = (int)(rem >> 9), c4 = (int)(rem & 511);
        u16x4 z = {0, 0, 0, 0};
        *(u16x4*)(xh + ((hb * NP) + NN + pn) * CC + c4 * 4) = z;
    }
}

// ---------------------------------------------------------------- k_castWv
__global__ __launch_bounds__(256) void k_castWv(const float* __restrict__ Wv,
                                                u16* __restrict__ Wvb)
{
    const size_t n4 = (size_t)HH * CC * CC / 4;
    const size_t stride = (size_t)gridDim.x * blockDim.x;
    for (size_t i = (size_t)blockIdx.x * blockDim.x + threadIdx.x; i < n4; i += stride) {
        float4 f = ((const float4*)Wv)[i];
        u16x4 u;
        u.x = f2bf(f.x); u.y = f2bf(f.y); u.z = f2bf(f.z); u.w = f2bf(f.w);
        ((u16x4*)Wvb)[i] = u;
    }
}

// ---------------------------------------------------------------- k_qk (fp32, unchanged)
__global__ __launch_bounds__(256) void k_qk(
    const float* __restrict__ bef, const float* __restrict__ dif,
    const float* __restrict__ Wq, const float* __restrict__ bq,
    const float* __restrict__ Wk, const float* __restrict__ bk,
    float* __restrict__ Qs, float* __restrict__ Ks)
{
    __shared__ float As[64][17];
    __shared__ float Bs[64][17];
    const int t  = threadIdx.x;
    const int mt = blockIdx.x >> 2, nt = blockIdx.x & 3;
    const int h  = blockIdx.y >> 4, b  = blockIdx.y & 15;
    const int isK = blockIdx.z;
    const float fh = (float)h;
    const int lr = t >> 2;
    const int lk = (t & 3) << 2;
    const int gm = mt * 64 + lr;
    const int go = nt * 64 + lr;
    const float* W = (isK ? Wk : Wq) + (size_t)h * C8 * CC;
    const float* Arow = bef + ((size_t)b * NN + gm) * CC + lk;
    const float* Drow = dif + ((size_t)b * NN + gm) * CC + lk;
    const float* Brow = W + (size_t)go * CC + lk;
    const int tr = t >> 4, tc = t & 15;
    float acc[4][4] = {{0.f}};

    for (int k0 = 0; k0 < CC; k0 += 16) {
        float4 av = make_float4(0.f, 0.f, 0.f, 0.f);
        if (gm < NN) {
            if (isK) {
                av = *(const float4*)(Drow + k0);
            } else {
                float4 xv = *(const float4*)(Arow + k0);
                float4 dv = *(const float4*)(Drow + k0);
                av.x = xv.x + fh * dv.x; av.y = xv.y + fh * dv.y;
                av.z = xv.z + fh * dv.z; av.w = xv.w + fh * dv.w;
            }
        }
        float4 wv = *(const float4*)(Brow + k0);
        As[lr][lk + 0] = av.x; As[lr][lk + 1] = av.y;
        As[lr][lk + 2] = av.z; As[lr][lk + 3] = av.w;
        Bs[lr][lk + 0] = wv.x; Bs[lr][lk + 1] = wv.y;
        Bs[lr][lk + 2] = wv.z; Bs[lr][lk + 3] = wv.w;
        __syncthreads();
#pragma unroll
        for (int kk = 0; kk < 16; ++kk) {
            float a[4], bb[4];
#pragma unroll
            for (int i = 0; i < 4; ++i) a[i] = As[tr * 4 + i][kk];
#pragma unroll
            for (int j = 0; j < 4; ++j) bb[j] = Bs[tc * 4 + j][kk];
#pragma unroll
            for (int i = 0; i < 4; ++i)
#pragma unroll
                for (int j = 0; j < 4; ++j)
                    acc[i][j] = fmaf(a[i], bb[j], acc[i][j]);
        }
        __syncthreads();
    }

    float* Out = isK ? Ks : Qs;
    const float* bias = isK ? bk : bq;
    const size_t obase = (size_t)(h * BB + b) * NN * C8;
#pragma unroll
    for (int i = 0; i < 4; ++i) {
        int m = mt * 64 + tr * 4 + i;
        if (m < NN) {
#pragma unroll
            for (int j = 0; j < 4; ++j) {
                int o = nt * 64 + tc * 4 + j;
                float v = isK ? (fh * acc[i][j] + bias[h * C8 + o])
                              : (acc[i][j] + bias[h * C8 + o]);
                Out[obase + (size_t)m * C8 + o] = v;
            }
        }
    }
}

// ---------------------------------------------------------------- k_energy (fp32, unchanged)
__global__ __launch_bounds__(256) void k_energy(
    const float* __restrict__ Qs, const float* __restrict__ Ks,
    float* __restrict__ E)
{
    __shared__ float As[64][17];
    __shared__ float Bs[64][17];
    const int t  = threadIdx.x;
    const int mt = blockIdx.x >> 2, nt = blockIdx.x & 3;
    const int hb = blockIdx.y;
    const int lr = t >> 2, lk = (t & 3) << 2;
    const int gn = mt * 64 + lr, gm = nt * 64 + lr;
    const float* Qrow = Qs + ((size_t)hb * NN + gn) * C8 + lk;
    const float* Krow = Ks + ((size_t)hb * NN + gm) * C8 + lk;
    const int tr = t >> 4, tc = t & 15;
    float acc[4][4] = {{0.f}};

    for (int k0 = 0; k0 < C8; k0 += 16) {
        float4 qv = make_float4(0.f, 0.f, 0.f, 0.f);
        float4 kv = make_float4(0.f, 0.f, 0.f, 0.f);
        if (gn < NN) qv = *(const float4*)(Qrow + k0);
        if (gm < NN) kv = *(const float4*)(Krow + k0);
        As[lr][lk + 0] = qv.x; As[lr][lk + 1] = qv.y;
        As[lr][lk + 2] = qv.z; As[lr][lk + 3] = qv.w;
        Bs[lr][lk + 0] = kv.x; Bs[lr][lk + 1] = kv.y;
        Bs[lr][lk + 2] = kv.z; Bs[lr][lk + 3] = kv.w;
        __syncthreads();
#pragma unroll
        for (int kk = 0; kk < 16; ++kk) {
            float a[4], bb[4];
#pragma unroll
            for (int i = 0; i < 4; ++i) a[i] = As[tr * 4 + i][kk];
#pragma unroll
            for (int j = 0; j < 4; ++j) bb[j] = Bs[tc * 4 + j][kk];
#pragma unroll
            for (int i = 0; i < 4; ++i)
#pragma unroll
                for (int j = 0; j < 4; ++j)
                    acc[i][j] = fmaf(a[i], bb[j], acc[i][j]);
        }
        __syncthreads();
    }
#pragma unroll
    for (int i = 0; i < 4; ++i) {
        int n = mt * 64 + tr * 4 + i;
        if (n < NN) {
#pragma unroll
            for (int j = 0; j < 4; ++j) {
                int m = nt * 64 + tc * 4 + j;
                if (m < NN)
                    E[(size_t)hb * NN * NN + (size_t)n * NN + m] = acc[i][j];
            }
        }
    }
}

// ---------------------------------------------------------------- k_softmax
// writes alphas (fp32, (B,1,N,N,H)) and padded bf16 attn [h][b][224][224]
__global__ __launch_bounds__(64) void k_softmax(const float* __restrict__ E,
                                                float* __restrict__ alphas,
                                                u16* __restrict__ atnb)
{
    const int r = blockIdx.x;                 // hb*224 + m
    const int t = threadIdx.x;
    const int hb = r / NP, m = r % NP;
    const int h = hb >> 4, b = hb & 15;
    u16* arow = atnb + ((size_t)hb * NP + m) * NP;
    if (m >= NN) {                            // pad row: zeros
#pragma unroll
        for (int j = 0; j < 4; ++j) {
            int idx = t + j * 64;
            if (idx < NP) arow[idx] = 0;
        }
        return;
    }
    const float* row = E + ((size_t)hb * NN + m) * NN;
    float v[4];
    float mx = -1e30f;
#pragma unroll
    for (int j = 0; j < 4; ++j) {
        int n = t + j * 64;
        v[j] = (n < NN) ? row[n] : -1e30f;
        mx = fmaxf(mx, v[j]);
    }
#pragma unroll
    for (int off = 32; off >= 1; off >>= 1) mx = fmaxf(mx, __shfl_xor(mx, off));
    float s = 0.f;
#pragma unroll
    for (int j = 0; j < 4; ++j) {
        int n = t + j * 64;
        if (n < NN) { v[j] = __expf(v[j] - mx); s += v[j]; }
    }
#pragma unroll
    for (int off = 32; off >= 1; off >>= 1) s += __shfl_xor(s, off);
    const float inv = 1.0f / s;
#pragma unroll
    for (int j = 0; j < 4; ++j) {
        int n = t + j * 64;
        if (n < NP) {
            float val = (n < NN) ? v[j] * inv : 0.f;
            if (n < NN)
                alphas[(((size_t)b * NN + m) * NN + n) * HH + h] = val;
            arow[n] = f2bf(val);
        }
    }
}

// ---------------------------------------------------------------- k_vpv (MFMA)
// block = (ct, h*16+b): V(128x224) = Wv_tile @ x ; out = gamma*V@P^T + x
__global__ __launch_bounds__(256, 2) void k_vpv(
    const u16* __restrict__ Wvb,   // [h][2048][2048]
    const u16* __restrict__ xh,    // [h][b][224][2048]
    const u16* __restrict__ atnb,  // [h][b][224][224]
    const float* __restrict__ bv,
    const float* __restrict__ gamma,
    u16* __restrict__ outs)        // [h][b][2048][196]
{
    // cells of 16B: Aw [0,512): g*128+o | Bx/P [512,1408): g*224+n | Vb [1408,4992): gn*128+c
    __shared__ u16 lds[4992 * 8];
    u16* Aw = lds;
    u16* Bx = lds + 512 * 8;
    u16* Vb = lds + 1408 * 8;

    const int t = threadIdx.x, w = t >> 6, ln = t & 63;
    const int lg = ln >> 4, l16 = ln & 15;
    const int wr = w >> 1, wc = w & 1;       // wave tile: 64c x 112n
    const int ct = blockIdx.x, h = blockIdx.y >> 4, b = blockIdx.y & 15;
    const size_t wv_base = ((size_t)h * CC + ct * 128) * CC;
    const size_t xh_base = (size_t)(h * BB + b) * NP * CC;
    const size_t p_base  = (size_t)(h * BB + b) * NP * NP;

    f32x4 acc[4][7];
    const f32x4 zf = {0.f, 0.f, 0.f, 0.f};
#pragma unroll
    for (int i = 0; i < 4; ++i)
#pragma unroll
        for (int j = 0; j < 7; ++j) acc[i][j] = zf;

    // ---------------- phase 1: V = Wv @ x
    for (int k0 = 0; k0 < CC; k0 += 32) {
#pragma unroll
        for (int it = 0; it < 2; ++it) {
            int cell = it * 256 + w * 64 + ln;
            int g = cell >> 7, o = cell & 127;
            cp16(Aw + (size_t)cell * 8, Wvb + wv_base + (size_t)o * CC + k0 + 8 * g);
        }
#pragma unroll
        for (int it = 0; it < 4; ++it) {
            if (it < 3 || w < 2) {
                int cell = it * 256 + w * 64 + ln;
                int g = cell / NP, n = cell % NP;
                cp16(Bx + (size_t)cell * 8, xh + xh_base + (size_t)n * CC + k0 + 8 * g);
            }
        }
        __syncthreads();
        bf16x8 a[4], bq[7];
#pragma unroll
        for (int i = 0; i < 4; ++i)
            a[i] = *(const bf16x8*)(Aw + (size_t)(lg * 128 + wr * 64 + i * 16 + l16) * 8);
#pragma unroll
        for (int j = 0; j < 7; ++j)
            bq[j] = *(const bf16x8*)(Bx + (size_t)(lg * NP + wc * 112 + j * 16 + l16) * 8);
#pragma unroll
        for (int i = 0; i < 4; ++i)
#pragma unroll
            for (int j = 0; j < 7; ++j)
                acc[i][j] = __builtin_amdgcn_mfma_f32_16x16x32_bf16(a[i], bq[j], acc[i][j], 0, 0, 0);
        __syncthreads();
    }

    // store V (+bias) to Vb: cell gn*128+c, word n&7
#pragma unroll
    for (int i = 0; i < 4; ++i) {
        int cb = wr * 64 + i * 16 + lg * 4;
#pragma unroll
        for (int j = 0; j < 7; ++j) {
            int n = wc * 112 + j * 16 + l16;
#pragma unroll
            for (int r = 0; r < 4; ++r) {
                float v = acc[i][j][r] + bv[h * CC + ct * 128 + cb + r];
                Vb[(size_t)((n >> 3) * 128 + cb + r) * 8 + (n & 7)] = f2bf(v);
            }
        }
    }
    __syncthreads();

    // ---------------- phase 2: out = V @ P^T
#pragma unroll
    for (int i = 0; i < 4; ++i)
#pragma unroll
        for (int j = 0; j < 7; ++j) acc[i][j] = zf;

    for (int s = 0; s < 7; ++s) {            // n0 = 32*s
#pragma unroll
        for (int it = 0; it < 4; ++it) {
            if (it < 3 || w < 2) {
                int cell = it * 256 + w * 64 + ln;
                int g = cell / NP, m = cell % NP;
                cp16(Bx + (size_t)cell * 8, atnb + p_base + (size_t)m * NP + s * 32 + 8 * g);
            }
        }
        __syncthreads();
        bf16x8 a[4], bq[7];
#pragma unroll
        for (int i = 0; i < 4; ++i)
            a[i] = *(const bf16x8*)(Vb + (size_t)((4 * s + lg) * 128 + wr * 64 + i * 16 + l16) * 8);
#pragma unroll
        for (int j = 0; j < 7; ++j)
            bq[j] = *(const bf16x8*)(Bx + (size_t)(lg * NP + wc * 112 + j * 16 + l16) * 8);
#pragma unroll
        for (int i = 0; i < 4; ++i)
#pragma unroll
            for (int j = 0; j < 7; ++j)
                acc[i][j] = __builtin_amdgcn_mfma_f32_16x16x32_bf16(a[i], bq[j], acc[i][j], 0, 0, 0);
        __syncthreads();
    }

    // ---------------- epilogue: out = gamma*acc + x, bf16 feats [c][m]
    const float gm = gamma[h];
    const size_t ob = ((size_t)(h * BB + b) * CC + ct * 128) * NN;
#pragma unroll
    for (int i = 0; i < 4; ++i) {
        int cb = wr * 64 + i * 16 + lg * 4;
#pragma unroll
        for (int j = 0; j < 7; ++j) {
            int m = wc * 112 + j * 16 + l16;
            if (m < NN) {
                const u16* xp = xh + xh_base + (size_t)m * CC + ct * 128 + cb;
#pragma unroll
                for (int r = 0; r < 4; ++r) {
                    float ov = gm * acc[i][j][r] + bf2f(xp[r]);
                    outs[ob + (size_t)(cb + r) * NN + m] = f2bf(ov);
                }
            }
        }
    }
}

// ---------------------------------------------------------------- k_lin (MFMA, split-K)
// part[ch][a][dm] over K-chunk ch (6272 each); A = feats bf16, B = Wl fp32->bf16
__global__ __launch_bounds__(256, 2) void k_lin(
    const u16* __restrict__ feats, const float* __restrict__ Wl,
    float* __restrict__ part)
{
    __shared__ u16 lds[(256 + 260) * 8];
    u16* Aa = lds;              // cell g*64+a
    u16* Bb = lds + 256 * 8;    // cell g*65+dm (padded)
    const int t = threadIdx.x, w = t >> 6, ln = t & 63;
    const int lg = ln >> 4, l16 = ln & 15;
    const int wr = w >> 1, wc = w & 1;      // wave: 32a x 32dm
    const int dmt = blockIdx.x, ch = blockIdx.y;
    const int ga = t >> 6, aa = t & 63;
    const u16* asrc = feats + (size_t)((aa & 3) * BB + (aa >> 2)) * FF + (size_t)ch * 6272 + 8 * ga;
    const int dmB = t >> 2, gB = t & 3;
    const float* bsrc = Wl + ((size_t)dmt * 64 + dmB) * FF + (size_t)ch * 6272 + 8 * gB;

    f32x4 acc[2][2];
    const f32x4 zf = {0.f, 0.f, 0.f, 0.f};
    acc[0][0] = zf; acc[0][1] = zf; acc[1][0] = zf; acc[1][1] = zf;

    for (int k0 = 0; k0 < 6272; k0 += 32) {
        cp16(Aa + (size_t)t * 8, asrc + k0);
        float4 f0 = *(const float4*)(bsrc + k0);
        float4 f1 = *(const float4*)(bsrc + k0 + 4);
        u16x8 bb;
        bb.s0 = f2bf(f0.x); bb.s1 = f2bf(f0.y); bb.s2 = f2bf(f0.z); bb.s3 = f2bf(f0.w);
        bb.s4 = f2bf(f1.x); bb.s5 = f2bf(f1.y); bb.s6 = f2bf(f1.z); bb.s7 = f2bf(f1.w);
        *(u16x8*)(Bb + (size_t)(gB * 65 + dmB) * 8) = bb;
        __syncthreads();
        bf16x8 a[2], bq[2];
#pragma unroll
        for (int i = 0; i < 2; ++i)
            a[i] = *(const bf16x8*)(Aa + (size_t)(lg * 64 + wr * 32 + i * 16 + l16) * 8);
#pragma unroll
        for (int j = 0; j < 2; ++j)
            bq[j] = *(const bf16x8*)(Bb + (size_t)(lg * 65 + wc * 32 + j * 16 + l16) * 8);
#pragma unroll
        for (int i = 0; i < 2; ++i)
#pragma unroll
            for (int j = 0; j < 2; ++j)
                acc[i][j] = __builtin_amdgcn_mfma_f32_16x16x32_bf16(a[i], bq[j], acc[i][j], 0, 0, 0);
        __syncthreads();
    }
#pragma unroll
    for (int i = 0; i < 2; ++i)
#pragma unroll
        for (int j = 0; j < 2; ++j)
#pragma unroll
            for (int r = 0; r < 4; ++r)
                part[((size_t)ch * 64 + wr * 32 + i * 16 + lg * 4 + r) * DM
                     + dmt * 64 + wc * 32 + j * 16 + l16] = acc[i][j][r];
}

// ---------------------------------------------------------------- k_red
__global__ __launch_bounds__(256) void k_red(const float* __restrict__ part,
                                             const float* __restrict__ bl,
                                             float* __restrict__ out0)
{
    int gid = blockIdx.x * 256 + threadIdx.x;
    if (gid < 64 * DM) {
        int dm = gid & (DM - 1);
        float s = bl[dm];
        for (int c2 = 0; c2 < 64; ++c2) s += part[(size_t)c2 * 64 * DM + gid];
        out0[gid] = s;
    }
}

// ---------------------------------------------------------------- launch
extern "C" void kernel_launch(void* const* d_in, const int* in_sizes, int n_in,
                              void* d_out, int out_size, void* d_ws, size_t ws_size,
                              hipStream_t stream)
{
    const float* bef   = (const float*)d_in[0];
    const float* aft   = (const float*)d_in[1];
    const float* Wq    = (const float*)d_in[2];
    const float* bq    = (const float*)d_in[3];
    const float* Wk    = (const float*)d_in[4];
    const float* bk    = (const float*)d_in[5];
    const float* Wv    = (const float*)d_in[6];
    const float* bv    = (const float*)d_in[7];
    const float* gamma = (const float*)d_in[8];
    const float* Wl    = (const float*)d_in[9];
    const float* bl    = (const float*)d_in[10];

    float* out0   = (float*)d_out;
    float* alphas = out0 + (size_t)BB * HH * DM;

    float* ws = (float*)d_ws;
    // fp32 region (units of f32):
    float* dif = ws;                          // [0, 6422528)
    float* Qs  = ws + 6422528;                // 3211264
    float* Ks  = ws + 9633792;                // 3211264
    float* E   = ws + 12845056;               // 2458624 -> ends 15303680
    // outs_bf16 aliases [0, 12845056) f32-equiv (dif/Qs/Ks dead by k_vpv)
    u16* outs = (u16*)ws;                     // 25690112 u16
    u16* xh   = (u16*)(ws + 15303680);        // 29360128 u16 -> +14680064 f32
    u16* Wvb  = (u16*)(ws + 29983744);        // 16777216 u16 -> +8388608 f32
    u16* atnb = (u16*)(ws + 38372352);        // 3211264 u16  -> +1605632 f32
    float* part = ws + 39977984;              // 2097152 -> ends 42075136 (~168 MB)

    k_prep<<<2048, 256, 0, stream>>>(bef, aft, dif, xh);
    k_castWv<<<2048, 256, 0, stream>>>(Wv, Wvb);
    k_qk<<<dim3(16, 64, 2), 256, 0, stream>>>(bef, dif, Wq, bq, Wk, bk, Qs, Ks);
    k_energy<<<dim3(16, 64), 256, 0, stream>>>(Qs, Ks, E);
    k_softmax<<<HH * BB * NP, 64, 0, stream>>>(E, alphas, atnb);
    k_vpv<<<dim3(16, 64), 256, 0, stream>>>(Wvb, xh, atnb, bv, gamma, outs);
    k_lin<<<dim3(8, 64), 256, 0, stream>>>(outs, Wl, part);
    k_red<<<128, 256, 0, stream>>>(part, bl, out0);
}

// Round 4
// 797.264 us; speedup vs baseline: 9.5682x; 1.5439x over previous
//
#include <hip/hip_runtime.h>
#include <hip/hip_bf16.h>

#define BB 16
#define NN 196
#define NP 224
#define CC 2048
#define C8 256
#define HH 4
#define DM 512
#define FF (CC*NN)   // 401408

typedef unsigned short u16;
typedef __attribute__((ext_vector_type(4))) u16 u16x4;
typedef __attribute__((ext_vector_type(8))) u16 u16x8;
typedef __attribute__((ext_vector_type(8))) short bf16x8;
typedef __attribute__((ext_vector_type(4))) float f32x4;

typedef __attribute__((address_space(1))) unsigned int as1_uint;
typedef __attribute__((address_space(3))) unsigned int as3_uint;

__device__ __forceinline__ void cp16(void* l, const void* g) {
    __builtin_amdgcn_global_load_lds((as1_uint*)g, (as3_uint*)l, 16, 0, 0);
}

__device__ __forceinline__ u16 f2bf(float f) {
    union { float f; unsigned u; } x; x.f = f;
    unsigned r = x.u + 0x7FFF + ((x.u >> 16) & 1);
    return (u16)(r >> 16);
}
__device__ __forceinline__ float bf2f(u16 u) {
    union { unsigned u; float f; } x; x.u = ((unsigned)u) << 16;
    return x.f;
}

// ---------------------------------------------------------------- k_prep
// hi/lo bf16 splits: xh/xl [h][b][224][2048], dh/dl [b][224][2048]
// (pad rows 196..223 zeroed)
__global__ __launch_bounds__(256) void k_prep(const float* __restrict__ bef,
                                              const float* __restrict__ aft,
                                              u16* __restrict__ xhi, u16* __restrict__ xlo,
                                              u16* __restrict__ dhi, u16* __restrict__ dlo)
{
    const float inv3 = 1.0f / 3.0f;
    const size_t n4 = (size_t)BB * NN * CC / 4;   // 1605632
    const size_t stride = (size_t)gridDim.x * blockDim.x;
    for (size_t i = (size_t)blockIdx.x * blockDim.x + threadIdx.x; i < n4; i += stride) {
        float4 a = ((const float4*)aft)[i];
        float4 b = ((const float4*)bef)[i];
        float4 d;
        d.x = (a.x - b.x) * inv3; d.y = (a.y - b.y) * inv3;
        d.z = (a.z - b.z) * inv3; d.w = (a.w - b.w) * inv3;
        size_t bn = i >> 9;
        int c = (int)(i & 511) * 4;
        int b_ = (int)(bn / NN), n = (int)(bn % NN);
        size_t dof = ((size_t)b_ * NP + n) * CC + c;
        u16x4 h4, l4;
        h4.x = f2bf(d.x); l4.x = f2bf(d.x - bf2f(h4.x));
        h4.y = f2bf(d.y); l4.y = f2bf(d.y - bf2f(h4.y));
        h4.z = f2bf(d.z); l4.z = f2bf(d.z - bf2f(h4.z));
        h4.w = f2bf(d.w); l4.w = f2bf(d.w - bf2f(h4.w));
        *(u16x4*)(dhi + dof) = h4;
        *(u16x4*)(dlo + dof) = l4;
#pragma unroll
        for (int h = 0; h < HH; ++h) {
            float fh = (float)h;
            float4 x;
            x.x = b.x + fh * d.x; x.y = b.y + fh * d.y;
            x.z = b.z + fh * d.z; x.w = b.w + fh * d.w;
            u16x4 xh4, xl4;
            xh4.x = f2bf(x.x); xl4.x = f2bf(x.x - bf2f(xh4.x));
            xh4.y = f2bf(x.y); xl4.y = f2bf(x.y - bf2f(xh4.y));
            xh4.z = f2bf(x.z); xl4.z = f2bf(x.z - bf2f(xh4.z));
            xh4.w = f2bf(x.w); xl4.w = f2bf(x.w - bf2f(xh4.w));
            size_t xof = ((size_t)(h * BB + b_) * NP + n) * CC + c;
            *(u16x4*)(xhi + xof) = xh4;
            *(u16x4*)(xlo + xof) = xl4;
        }
    }
    // zero pad rows
    const size_t dpad = (size_t)BB * (NP - NN) * CC / 4;      // 229376
    const u16x4 z4 = {0, 0, 0, 0};
    for (size_t i = (size_t)blockIdx.x * blockDim.x + threadIdx.x; i < dpad; i += stride) {
        size_t b_ = i / ((NP - NN) * CC / 4);
        size_t rem = i % ((NP - NN) * CC / 4);
        int pn = (int)(rem >> 9), c4 = (int)(rem & 511);
        size_t of = ((size_t)b_ * NP + NN + pn) * CC + c4 * 4;
        *(u16x4*)(dhi + of) = z4; *(u16x4*)(dlo + of) = z4;
    }
    const size_t xpad = (size_t)HH * BB * (NP - NN) * CC / 4; // 917504
    for (size_t i = (size_t)blockIdx.x * blockDim.x + threadIdx.x; i < xpad; i += stride) {
        size_t hb = i / ((NP - NN) * CC / 4);
        size_t rem = i % ((NP - NN) * CC / 4);
        int pn = (int)(rem >> 9), c4 = (int)(rem & 511);
        size_t of = ((size_t)hb * NP + NN + pn) * CC + c4 * 4;
        *(u16x4*)(xhi + of) = z4; *(u16x4*)(xlo + of) = z4;
    }
}

// ---------------------------------------------------------------- k_castQK
__global__ __launch_bounds__(256) void k_castQK(const float* __restrict__ Wq,
                                                const float* __restrict__ Wk,
                                                u16* __restrict__ wqh, u16* __restrict__ wql,
                                                u16* __restrict__ wkh, u16* __restrict__ wkl)
{
    const size_t half = (size_t)HH * C8 * CC / 4;   // 524288
    const size_t tot = half * 2;
    const size_t stride = (size_t)gridDim.x * blockDim.x;
    for (size_t i = (size_t)blockIdx.x * blockDim.x + threadIdx.x; i < tot; i += stride) {
        const float* src; u16* dh; u16* dl; size_t j;
        if (i < half) { src = Wq; dh = wqh; dl = wql; j = i; }
        else          { src = Wk; dh = wkh; dl = wkl; j = i - half; }
        float4 f = ((const float4*)src)[j];
        u16x4 h4, l4;
        h4.x = f2bf(f.x); l4.x = f2bf(f.x - bf2f(h4.x));
        h4.y = f2bf(f.y); l4.y = f2bf(f.y - bf2f(h4.y));
        h4.z = f2bf(f.z); l4.z = f2bf(f.z - bf2f(h4.z));
        h4.w = f2bf(f.w); l4.w = f2bf(f.w - bf2f(h4.w));
        ((u16x4*)dh)[j] = h4; ((u16x4*)dl)[j] = l4;
    }
}

// ---------------------------------------------------------------- k_castWv
__global__ __launch_bounds__(256) void k_castWv(const float* __restrict__ Wv,
                                                u16* __restrict__ Wvb)
{
    const size_t n4 = (size_t)HH * CC * CC / 4;
    const size_t stride = (size_t)gridDim.x * blockDim.x;
    for (size_t i = (size_t)blockIdx.x * blockDim.x + threadIdx.x; i < n4; i += stride) {
        float4 f = ((const float4*)Wv)[i];
        u16x4 u;
        u.x = f2bf(f.x); u.y = f2bf(f.y); u.z = f2bf(f.z); u.w = f2bf(f.w);
        ((u16x4*)Wvb)[i] = u;
    }
}

// ---------------------------------------------------------------- k_qkm
// split-bf16 MFMA GEMM. z=0: Q = x_h @ Wq_h^T + bq (A=xhi/xlo indexed by hb)
//                       z=1: K = h*(dif @ Wk_h^T) + bk (A=dhi/dlo indexed by b)
// out fp32 [hb][o 256][n 224]
__global__ __launch_bounds__(256, 2) void k_qkm(
    const u16* __restrict__ Ahi, const u16* __restrict__ Alo,
    const u16* __restrict__ Whi, const u16* __restrict__ Wlo,
    const float* __restrict__ biasIn,
    float* __restrict__ Out, const int z)
{
    // cells of 16B: Wh [0,512) Wl [512,1024) Xh [1024,1472) Xl [1472,1920)
    __shared__ u16 lds[1920 * 8];
    u16* Wh = lds;
    u16* Wl_ = lds + 512 * 8;
    u16* Xh = lds + 1024 * 8;
    u16* Xl = lds + 1472 * 8;

    const int t = threadIdx.x, w = t >> 6, ln = t & 63;
    const int lg = ln >> 4, l16 = ln & 15;
    const int ct = blockIdx.x & 1, mt = blockIdx.x >> 1;
    const int hb = blockIdx.y, h = hb >> 4, b = hb & 15;

    const u16* Ah = Ahi + ((size_t)(z ? b : hb) * NP + mt * 112) * CC;
    const u16* Al = Alo + ((size_t)(z ? b : hb) * NP + mt * 112) * CC;
    const u16* Bh = Whi + ((size_t)h * C8 + ct * 128) * CC;
    const u16* Bl = Wlo + ((size_t)h * C8 + ct * 128) * CC;
    const float scale = z ? (float)h : 1.0f;
    const float* bias = biasIn + h * C8;

    f32x4 acc[2][7];
    const f32x4 zf = {0.f, 0.f, 0.f, 0.f};
#pragma unroll
    for (int i = 0; i < 2; ++i)
#pragma unroll
        for (int j = 0; j < 7; ++j) acc[i][j] = zf;

    for (int k0 = 0; k0 < CC; k0 += 32) {
#pragma unroll
        for (int it = 0; it < 2; ++it) {
            int cell = it * 256 + t;
            int g = cell >> 7, o = cell & 127;
            cp16(Wh + (size_t)cell * 8, Bh + (size_t)o * CC + k0 + 8 * g);
            cp16(Wl_ + (size_t)cell * 8, Bl + (size_t)o * CC + k0 + 8 * g);
        }
        {
            int g = t / 112, n = t % 112;
            cp16(Xh + (size_t)t * 8, Ah + (size_t)n * CC + k0 + 8 * g);
            cp16(Xl + (size_t)t * 8, Al + (size_t)n * CC + k0 + 8 * g);
            if (t < 192) {
                int cell = 256 + t;
                int g2 = cell / 112, n2 = cell % 112;
                cp16(Xh + (size_t)cell * 8, Ah + (size_t)n2 * CC + k0 + 8 * g2);
                cp16(Xl + (size_t)cell * 8, Al + (size_t)n2 * CC + k0 + 8 * g2);
            }
        }
        __syncthreads();
        bf16x8 ah[2], al[2], bh[7], bl[7];
#pragma unroll
        for (int i = 0; i < 2; ++i) {
            ah[i] = *(const bf16x8*)(Wh + (size_t)(lg * 128 + w * 32 + i * 16 + l16) * 8);
            al[i] = *(const bf16x8*)(Wl_ + (size_t)(lg * 128 + w * 32 + i * 16 + l16) * 8);
        }
#pragma unroll
        for (int j = 0; j < 7; ++j) {
            bh[j] = *(const bf16x8*)(Xh + (size_t)(lg * 112 + j * 16 + l16) * 8);
            bl[j] = *(const bf16x8*)(Xl + (size_t)(lg * 112 + j * 16 + l16) * 8);
        }
#pragma unroll
        for (int i = 0; i < 2; ++i)
#pragma unroll
            for (int j = 0; j < 7; ++j)
                acc[i][j] = __builtin_amdgcn_mfma_f32_16x16x32_bf16(ah[i], bh[j], acc[i][j], 0, 0, 0);
#pragma unroll
        for (int i = 0; i < 2; ++i)
#pragma unroll
            for (int j = 0; j < 7; ++j)
                acc[i][j] = __builtin_amdgcn_mfma_f32_16x16x32_bf16(ah[i], bl[j], acc[i][j], 0, 0, 0);
#pragma unroll
        for (int i = 0; i < 2; ++i)
#pragma unroll
            for (int j = 0; j < 7; ++j)
                acc[i][j] = __builtin_amdgcn_mfma_f32_16x16x32_bf16(al[i], bh[j], acc[i][j], 0, 0, 0);
        __syncthreads();
    }

#pragma unroll
    for (int i = 0; i < 2; ++i) {
        int ob = ct * 128 + w * 32 + i * 16 + lg * 4;
#pragma unroll
        for (int j = 0; j < 7; ++j) {
            int n = mt * 112 + j * 16 + l16;
#pragma unroll
            for (int r = 0; r < 4; ++r) {
                int o = ob + r;
                Out[((size_t)hb * C8 + o) * NP + n] = scale * acc[i][j][r] + bias[o];
            }
        }
    }
}

// ---------------------------------------------------------------- k_esm
// fused energy (fp32 VALU) + row softmax; writes alphas fp32 + padded bf16 atnb
__global__ __launch_bounds__(256, 2) void k_esm(
    const float* __restrict__ Qf, const float* __restrict__ Kf,
    float* __restrict__ alphas, u16* __restrict__ atnb)
{
    __shared__ float Qt[256][32];
    __shared__ float Kt[256][32];
    __shared__ float red[32][8];

    const int t = threadIdx.x;
    const int ml = t & 31, q = t >> 5;
    const int mt = blockIdx.x, hb = blockIdx.y;
    const int h = hb >> 4, b = hb & 15;
    const int m0 = mt * 32, m = m0 + ml;

#pragma unroll 4
    for (int j2 = 0; j2 < 32; ++j2) {
        int idx = t + 256 * j2;
        int o = idx >> 5, mm = idx & 31;
        Qt[o][mm] = Qf[((size_t)hb * C8 + o) * NP + m0 + mm];
    }

    float e[28];
#pragma unroll
    for (int nt = 0; nt < 7; ++nt) {
        __syncthreads();
        int n0 = nt * 32;
#pragma unroll 4
        for (int j2 = 0; j2 < 32; ++j2) {
            int idx = t + 256 * j2;
            int o = idx >> 5, nn = idx & 31;
            Kt[o][nn] = Kf[((size_t)hb * C8 + o) * NP + n0 + nn];
        }
        __syncthreads();
        float e0 = 0.f, e1 = 0.f, e2 = 0.f, e3 = 0.f;
#pragma unroll 8
        for (int o = 0; o < 256; ++o) {
            float qv = Qt[o][ml];
            e0 = fmaf(qv, Kt[o][q * 4 + 0], e0);
            e1 = fmaf(qv, Kt[o][q * 4 + 1], e1);
            e2 = fmaf(qv, Kt[o][q * 4 + 2], e2);
            e3 = fmaf(qv, Kt[o][q * 4 + 3], e3);
        }
        e[nt * 4 + 0] = e0; e[nt * 4 + 1] = e1;
        e[nt * 4 + 2] = e2; e[nt * 4 + 3] = e3;
    }
    __syncthreads();

    const bool mval = (m < NN);
    float mx = -1e30f;
#pragma unroll
    for (int nt = 0; nt < 7; ++nt)
#pragma unroll
        for (int i = 0; i < 4; ++i) {
            int n = nt * 32 + q * 4 + i;
            if (n < NN) mx = fmaxf(mx, e[nt * 4 + i]);
        }
    red[ml][q] = mx;
    __syncthreads();
    mx = red[ml][0];
#pragma unroll
    for (int k = 1; k < 8; ++k) mx = fmaxf(mx, red[ml][k]);
    __syncthreads();
    float s = 0.f;
#pragma unroll
    for (int nt = 0; nt < 7; ++nt)
#pragma unroll
        for (int i = 0; i < 4; ++i) {
            int n = nt * 32 + q * 4 + i;
            if (n < NN) { e[nt * 4 + i] = __expf(e[nt * 4 + i] - mx); s += e[nt * 4 + i]; }
        }
    red[ml][q] = s;
    __syncthreads();
    s = red[ml][0];
#pragma unroll
    for (int k = 1; k < 8; ++k) s += red[ml][k];
    const float inv = 1.0f / s;

    u16* arow = atnb + ((size_t)hb * NP + m) * NP;
#pragma unroll
    for (int nt = 0; nt < 7; ++nt)
#pragma unroll
        for (int i = 0; i < 4; ++i) {
            int n = nt * 32 + q * 4 + i;
            float a = (mval && n < NN) ? e[nt * 4 + i] * inv : 0.f;
            arow[n] = f2bf(a);
            if (mval && n < NN)
                alphas[(((size_t)b * NN + m) * NN + n) * HH + h] = a;
        }
}

// ---------------------------------------------------------------- k_vpv (MFMA)
__global__ __launch_bounds__(256, 2) void k_vpv(
    const u16* __restrict__ Wvb,   // [h][2048][2048]
    const u16* __restrict__ xhi,   // [h][b][224][2048]
    const u16* __restrict__ atnb,  // [h][b][224][224]
    const float* __restrict__ bv,
    const float* __restrict__ gamma,
    u16* __restrict__ outs)        // [h][b][2048][196]
{
    __shared__ u16 lds[4992 * 8];
    u16* Aw = lds;
    u16* Bx = lds + 512 * 8;
    u16* Vb = lds + 1408 * 8;

    const int t = threadIdx.x, w = t >> 6, ln = t & 63;
    const int lg = ln >> 4, l16 = ln & 15;
    const int wr = w >> 1, wc = w & 1;
    const int ct = blockIdx.x, h = blockIdx.y >> 4, b = blockIdx.y & 15;
    const size_t wv_base = ((size_t)h * CC + ct * 128) * CC;
    const size_t xh_base = (size_t)(h * BB + b) * NP * CC;
    const size_t p_base  = (size_t)(h * BB + b) * NP * NP;

    f32x4 acc[4][7];
    const f32x4 zf = {0.f, 0.f, 0.f, 0.f};
#pragma unroll
    for (int i = 0; i < 4; ++i)
#pragma unroll
        for (int j = 0; j < 7; ++j) acc[i][j] = zf;

    // phase 1: V = Wv @ x
    for (int k0 = 0; k0 < CC; k0 += 32) {
#pragma unroll
        for (int it = 0; it < 2; ++it) {
            int cell = it * 256 + w * 64 + ln;
            int g = cell >> 7, o = cell & 127;
            cp16(Aw + (size_t)cell * 8, Wvb + wv_base + (size_t)o * CC + k0 + 8 * g);
        }
#pragma unroll
        for (int it = 0; it < 4; ++it) {
            if (it < 3 || w < 2) {
                int cell = it * 256 + w * 64 + ln;
                int g = cell / NP, n = cell % NP;
                cp16(Bx + (size_t)cell * 8, xhi + xh_base + (size_t)n * CC + k0 + 8 * g);
            }
        }
        __syncthreads();
        bf16x8 a[4], bq[7];
#pragma unroll
        for (int i = 0; i < 4; ++i)
            a[i] = *(const bf16x8*)(Aw + (size_t)(lg * 128 + wr * 64 + i * 16 + l16) * 8);
#pragma unroll
        for (int j = 0; j < 7; ++j)
            bq[j] = *(const bf16x8*)(Bx + (size_t)(lg * NP + wc * 112 + j * 16 + l16) * 8);
#pragma unroll
        for (int i = 0; i < 4; ++i)
#pragma unroll
            for (int j = 0; j < 7; ++j)
                acc[i][j] = __builtin_amdgcn_mfma_f32_16x16x32_bf16(a[i], bq[j], acc[i][j], 0, 0, 0);
        __syncthreads();
    }

    // park V (+bias) in LDS
#pragma unroll
    for (int i = 0; i < 4; ++i) {
        int cb = wr * 64 + i * 16 + lg * 4;
#pragma unroll
        for (int j = 0; j < 7; ++j) {
            int n = wc * 112 + j * 16 + l16;
#pragma unroll
            for (int r = 0; r < 4; ++r) {
                float v = acc[i][j][r] + bv[h * CC + ct * 128 + cb + r];
                Vb[(size_t)((n >> 3) * 128 + cb + r) * 8 + (n & 7)] = f2bf(v);
            }
        }
    }
    __syncthreads();

    // phase 2: out = V @ P^T
#pragma unroll
    for (int i = 0; i < 4; ++i)
#pragma unroll
        for (int j = 0; j < 7; ++j) acc[i][j] = zf;

    for (int s = 0; s < 7; ++s) {
#pragma unroll
        for (int it = 0; it < 4; ++it) {
            if (it < 3 || w < 2) {
                int cell = it * 256 + w * 64 + ln;
                int g = cell / NP, m = cell % NP;
                cp16(Bx + (size_t)cell * 8, atnb + p_base + (size_t)m * NP + s * 32 + 8 * g);
            }
        }
        __syncthreads();
        bf16x8 a[4], bq[7];
#pragma unroll
        for (int i = 0; i < 4; ++i)
            a[i] = *(const bf16x8*)(Vb + (size_t)((4 * s + lg) * 128 + wr * 64 + i * 16 + l16) * 8);
#pragma unroll
        for (int j = 0; j < 7; ++j)
            bq[j] = *(const bf16x8*)(Bx + (size_t)(lg * NP + wc * 112 + j * 16 + l16) * 8);
#pragma unroll
        for (int i = 0; i < 4; ++i)
#pragma unroll
            for (int j = 0; j < 7; ++j)
                acc[i][j] = __builtin_amdgcn_mfma_f32_16x16x32_bf16(a[i], bq[j], acc[i][j], 0, 0, 0);
        __syncthreads();
    }

    // epilogue
    const float gm = gamma[h];
    const size_t ob = ((size_t)(h * BB + b) * CC + ct * 128) * NN;
#pragma unroll
    for (int i = 0; i < 4; ++i) {
        int cb = wr * 64 + i * 16 + lg * 4;
#pragma unroll
        for (int j = 0; j < 7; ++j) {
            int m = wc * 112 + j * 16 + l16;
            if (m < NN) {
                const u16* xp = xhi + xh_base + (size_t)m * CC + ct * 128 + cb;
#pragma unroll
                for (int r = 0; r < 4; ++r) {
                    float ov = gm * acc[i][j][r] + bf2f(xp[r]);
                    outs[ob + (size_t)(cb + r) * NN + m] = f2bf(ov);
                }
            }
        }
    }
}

// ---------------------------------------------------------------- k_lin (MFMA, split-K)
__global__ __launch_bounds__(256, 2) void k_lin(
    const u16* __restrict__ feats, const float* __restrict__ Wl,
    float* __restrict__ part)
{
    __shared__ u16 lds[(256 + 260) * 8];
    u16* Aa = lds;
    u16* Bb = lds + 256 * 8;
    const int t = threadIdx.x, w = t >> 6, ln = t & 63;
    const int lg = ln >> 4, l16 = ln & 15;
    const int wr = w >> 1, wc = w & 1;
    const int dmt = blockIdx.x, ch = blockIdx.y;
    const int ga = t >> 6, aa = t & 63;
    const u16* asrc = feats + (size_t)((aa & 3) * BB + (aa >> 2)) * FF + (size_t)ch * 6272 + 8 * ga;
    const int dmB = t >> 2, gB = t & 3;
    const float* bsrc = Wl + ((size_t)dmt * 64 + dmB) * FF + (size_t)ch * 6272 + 8 * gB;

    f32x4 acc[2][2];
    const f32x4 zf = {0.f, 0.f, 0.f, 0.f};
    acc[0][0] = zf; acc[0][1] = zf; acc[1][0] = zf; acc[1][1] = zf;

    for (int k0 = 0; k0 < 6272; k0 += 32) {
        cp16(Aa + (size_t)t * 8, asrc + k0);
        float4 f0 = *(const float4*)(bsrc + k0);
        float4 f1 = *(const float4*)(bsrc + k0 + 4);
        u16x8 bb;
        bb.s0 = f2bf(f0.x); bb.s1 = f2bf(f0.y); bb.s2 = f2bf(f0.z); bb.s3 = f2bf(f0.w);
        bb.s4 = f2bf(f1.x); bb.s5 = f2bf(f1.y); bb.s6 = f2bf(f1.z); bb.s7 = f2bf(f1.w);
        *(u16x8*)(Bb + (size_t)(gB * 65 + dmB) * 8) = bb;
        __syncthreads();
        bf16x8 a[2], bq[2];
#pragma unroll
        for (int i = 0; i < 2; ++i)
            a[i] = *(const bf16x8*)(Aa + (size_t)(lg * 64 + wr * 32 + i * 16 + l16) * 8);
#pragma unroll
        for (int j = 0; j < 2; ++j)
            bq[j] = *(const bf16x8*)(Bb + (size_t)(lg * 65 + wc * 32 + j * 16 + l16) * 8);
#pragma unroll
        for (int i = 0; i < 2; ++i)
#pragma unroll
            for (int j = 0; j < 2; ++j)
                acc[i][j] = __builtin_amdgcn_mfma_f32_16x16x32_bf16(a[i], bq[j], acc[i][j], 0, 0, 0);
        __syncthreads();
    }
#pragma unroll
    for (int i = 0; i < 2; ++i)
#pragma unroll
        for (int j = 0; j < 2; ++j)
#pragma unroll
            for (int r = 0; r < 4; ++r)
                part[((size_t)ch * 64 + wr * 32 + i * 16 + lg * 4 + r) * DM
                     + dmt * 64 + wc * 32 + j * 16 + l16] = acc[i][j][r];
}

// ---------------------------------------------------------------- k_red
__global__ __launch_bounds__(256) void k_red(const float* __restrict__ part,
                                             const float* __restrict__ bl,
                                             float* __restrict__ out0)
{
    int gid = blockIdx.x * 256 + threadIdx.x;
    if (gid < 64 * DM) {
        int dm = gid & (DM - 1);
        float s = bl[dm];
        for (int c2 = 0; c2 < 64; ++c2) s += part[(size_t)c2 * 64 * DM + gid];
        out0[gid] = s;
    }
}

// ---------------------------------------------------------------- launch
extern "C" void kernel_launch(void* const* d_in, const int* in_sizes, int n_in,
                              void* d_out, int out_size, void* d_ws, size_t ws_size,
                              hipStream_t stream)
{
    const float* bef   = (const float*)d_in[0];
    const float* aft   = (const float*)d_in[1];
    const float* Wq    = (const float*)d_in[2];
    const float* bq    = (const float*)d_in[3];
    const float* Wk    = (const float*)d_in[4];
    const float* bk    = (const float*)d_in[5];
    const float* Wv    = (const float*)d_in[6];
    const float* bv    = (const float*)d_in[7];
    const float* gamma = (const float*)d_in[8];
    const float* Wl    = (const float*)d_in[9];
    const float* bl    = (const float*)d_in[10];

    float* out0   = (float*)d_out;
    float* alphas = out0 + (size_t)BB * HH * DM;

    float* ws = (float*)d_ws;
    // ---- f32-unit layout (sizes in f32 words) ----
    // xhi  [0,          14,680,064)   live: k_prep .. k_vpv
    // xlo  [14,680,064, 29,360,128)   live: k_prep .. k_qkm(Q)
    // dhi  [29,360,128, 33,030,144)   live: k_prep .. k_qkm(K)   (3,670,016 each!)
    // dlo  [33,030,144, 36,700,160)
    // wqh  [36,700,160, 37,748,736)   wql [.., 38,797,312)
    // wkh  [38,797,312, 39,845,888)   wkl [.., 40,894,464)
    // Qf   [40,894,464, 44,564,480)   live: k_qkm(Q) .. k_esm     PEAK = 178.3 MB
    u16* xhi  = (u16*)ws;
    u16* xlo  = (u16*)(ws + 14680064);
    u16* dhi  = (u16*)(ws + 29360128);
    u16* dlo  = (u16*)(ws + 33030144);
    u16* wqh  = (u16*)(ws + 36700160);
    u16* wql  = (u16*)(ws + 37748736);
    u16* wkh  = (u16*)(ws + 38797312);
    u16* wkl  = (u16*)(ws + 39845888);
    float* Qf = ws + 40894464;
    // aliases (writer strictly after previous reader on stream):
    float* Kf   = ws + 14680064;            // in dead xlo (k_qkm K after Q)
    u16* Wvb    = (u16*)(ws + 29360128);    // over dead dhi/dlo/wqh (after QK passes)
    u16* atnb   = (u16*)(ws + 37748736);    // over dead wql/wkh
    float* part = ws + 39354368;            // over dead wkl + Qf head (after k_esm)
    u16* outs   = (u16*)(ws + 14680064);    // over dead xlo/Kf (after k_esm)

    k_prep<<<2048, 256, 0, stream>>>(bef, aft, xhi, xlo, dhi, dlo);
    k_castQK<<<1024, 256, 0, stream>>>(Wq, Wk, wqh, wql, wkh, wkl);
    k_qkm<<<dim3(4, 64), 256, 0, stream>>>(xhi, xlo, wqh, wql, bq, Qf, 0);
    k_qkm<<<dim3(4, 64), 256, 0, stream>>>(dhi, dlo, wkh, wkl, bk, Kf, 1);
    k_castWv<<<2048, 256, 0, stream>>>(Wv, Wvb);
    k_esm<<<dim3(7, 64), 256, 0, stream>>>(Qf, Kf, alphas, atnb);
    k_vpv<<<dim3(16, 64), 256, 0, stream>>>(Wvb, xhi, atnb, bv, gamma, outs);
    k_lin<<<dim3(8, 64), 256, 0, stream>>>(outs, Wl, part);
    k_red<<<128, 256, 0, stream>>>(part, bl, out0);
}

// Round 5
// 760.595 us; speedup vs baseline: 10.0295x; 1.0482x over previous
//
#include <hip/hip_runtime.h>
#include <hip/hip_bf16.h>

#define BB 16
#define NN 196
#define NP 224
#define CC 2048
#define C8 256
#define HH 4
#define DM 512
#define FF (CC*NN)   // 401408

typedef unsigned short u16;
typedef __attribute__((ext_vector_type(4))) u16 u16x4;
typedef __attribute__((ext_vector_type(8))) u16 u16x8;
typedef __attribute__((ext_vector_type(8))) short bf16x8;
typedef __attribute__((ext_vector_type(4))) float f32x4;

typedef __attribute__((address_space(1))) unsigned int as1_uint;
typedef __attribute__((address_space(3))) unsigned int as3_uint;

__device__ __forceinline__ void cp16(void* l, const void* g) {
    __builtin_amdgcn_global_load_lds((as1_uint*)g, (as3_uint*)l, 16, 0, 0);
}

__device__ __forceinline__ u16 f2bf(float f) {
    union { float f; unsigned u; } x; x.f = f;
    unsigned r = x.u + 0x7FFF + ((x.u >> 16) & 1);
    return (u16)(r >> 16);
}
__device__ __forceinline__ float bf2f(u16 u) {
    union { unsigned u; float f; } x; x.u = ((unsigned)u) << 16;
    return x.f;
}

// ---------------------------------------------------------------- k_prep
// hi/lo bf16 splits: xh/xl [h][b][224][2048], dh/dl [b][224][2048]
// (pad rows 196..223 zeroed)
__global__ __launch_bounds__(256) void k_prep(const float* __restrict__ bef,
                                              const float* __restrict__ aft,
                                              u16* __restrict__ xhi, u16* __restrict__ xlo,
                                              u16* __restrict__ dhi, u16* __restrict__ dlo)
{
    const float inv3 = 1.0f / 3.0f;
    const size_t n4 = (size_t)BB * NN * CC / 4;   // 1605632
    const size_t stride = (size_t)gridDim.x * blockDim.x;
    for (size_t i = (size_t)blockIdx.x * blockDim.x + threadIdx.x; i < n4; i += stride) {
        float4 a = ((const float4*)aft)[i];
        float4 b = ((const float4*)bef)[i];
        float4 d;
        d.x = (a.x - b.x) * inv3; d.y = (a.y - b.y) * inv3;
        d.z = (a.z - b.z) * inv3; d.w = (a.w - b.w) * inv3;
        size_t bn = i >> 9;
        int c = (int)(i & 511) * 4;
        int b_ = (int)(bn / NN), n = (int)(bn % NN);
        size_t dof = ((size_t)b_ * NP + n) * CC + c;
        u16x4 h4, l4;
        h4.x = f2bf(d.x); l4.x = f2bf(d.x - bf2f(h4.x));
        h4.y = f2bf(d.y); l4.y = f2bf(d.y - bf2f(h4.y));
        h4.z = f2bf(d.z); l4.z = f2bf(d.z - bf2f(h4.z));
        h4.w = f2bf(d.w); l4.w = f2bf(d.w - bf2f(h4.w));
        *(u16x4*)(dhi + dof) = h4;
        *(u16x4*)(dlo + dof) = l4;
#pragma unroll
        for (int h = 0; h < HH; ++h) {
            float fh = (float)h;
            float4 x;
            x.x = b.x + fh * d.x; x.y = b.y + fh * d.y;
            x.z = b.z + fh * d.z; x.w = b.w + fh * d.w;
            u16x4 xh4, xl4;
            xh4.x = f2bf(x.x); xl4.x = f2bf(x.x - bf2f(xh4.x));
            xh4.y = f2bf(x.y); xl4.y = f2bf(x.y - bf2f(xh4.y));
            xh4.z = f2bf(x.z); xl4.z = f2bf(x.z - bf2f(xh4.z));
            xh4.w = f2bf(x.w); xl4.w = f2bf(x.w - bf2f(xh4.w));
            size_t xof = ((size_t)(h * BB + b_) * NP + n) * CC + c;
            *(u16x4*)(xhi + xof) = xh4;
            *(u16x4*)(xlo + xof) = xl4;
        }
    }
    // zero pad rows
    const size_t dpad = (size_t)BB * (NP - NN) * CC / 4;      // 229376
    const u16x4 z4 = {0, 0, 0, 0};
    for (size_t i = (size_t)blockIdx.x * blockDim.x + threadIdx.x; i < dpad; i += stride) {
        size_t b_ = i / ((NP - NN) * CC / 4);
        size_t rem = i % ((NP - NN) * CC / 4);
        int pn = (int)(rem >> 9), c4 = (int)(rem & 511);
        size_t of = ((size_t)b_ * NP + NN + pn) * CC + c4 * 4;
        *(u16x4*)(dhi + of) = z4; *(u16x4*)(dlo + of) = z4;
    }
    const size_t xpad = (size_t)HH * BB * (NP - NN) * CC / 4; // 917504
    for (size_t i = (size_t)blockIdx.x * blockDim.x + threadIdx.x; i < xpad; i += stride) {
        size_t hb = i / ((NP - NN) * CC / 4);
        size_t rem = i % ((NP - NN) * CC / 4);
        int pn = (int)(rem >> 9), c4 = (int)(rem & 511);
        size_t of = ((size_t)hb * NP + NN + pn) * CC + c4 * 4;
        *(u16x4*)(xhi + of) = z4; *(u16x4*)(xlo + of) = z4;
    }
}

// ---------------------------------------------------------------- k_castQK
__global__ __launch_bounds__(256) void k_castQK(const float* __restrict__ Wq,
                                                const float* __restrict__ Wk,
                                                u16* __restrict__ wqh, u16* __restrict__ wql,
                                                u16* __restrict__ wkh, u16* __restrict__ wkl)
{
    const size_t half = (size_t)HH * C8 * CC / 4;   // 524288
    const size_t tot = half * 2;
    const size_t stride = (size_t)gridDim.x * blockDim.x;
    for (size_t i = (size_t)blockIdx.x * blockDim.x + threadIdx.x; i < tot; i += stride) {
        const float* src; u16* dh; u16* dl; size_t j;
        if (i < half) { src = Wq; dh = wqh; dl = wql; j = i; }
        else          { src = Wk; dh = wkh; dl = wkl; j = i - half; }
        float4 f = ((const float4*)src)[j];
        u16x4 h4, l4;
        h4.x = f2bf(f.x); l4.x = f2bf(f.x - bf2f(h4.x));
        h4.y = f2bf(f.y); l4.y = f2bf(f.y - bf2f(h4.y));
        h4.z = f2bf(f.z); l4.z = f2bf(f.z - bf2f(h4.z));
        h4.w = f2bf(f.w); l4.w = f2bf(f.w - bf2f(h4.w));
        ((u16x4*)dh)[j] = h4; ((u16x4*)dl)[j] = l4;
    }
}

// ---------------------------------------------------------------- k_castWv
__global__ __launch_bounds__(256) void k_castWv(const float* __restrict__ Wv,
                                                u16* __restrict__ Wvb)
{
    const size_t n4 = (size_t)HH * CC * CC / 4;
    const size_t stride = (size_t)gridDim.x * blockDim.x;
    for (size_t i = (size_t)blockIdx.x * blockDim.x + threadIdx.x; i < n4; i += stride) {
        float4 f = ((const float4*)Wv)[i];
        u16x4 u;
        u.x = f2bf(f.x); u.y = f2bf(f.y); u.z = f2bf(f.z); u.w = f2bf(f.w);
        ((u16x4*)Wvb)[i] = u;
    }
}

// ---------------------------------------------------------------- k_qkm
// split-bf16 MFMA GEMM. z=0: Q = x_h @ Wq_h^T + bq (A indexed by hb)
//                       z=1: K = h*(dif @ Wk_h^T) + bk (A indexed by b)
// outputs hi/lo bf16, layout [hb][n 224][o 256]
__global__ __launch_bounds__(256, 2) void k_qkm(
    const u16* __restrict__ Ahi, const u16* __restrict__ Alo,
    const u16* __restrict__ Whi, const u16* __restrict__ Wlo,
    const float* __restrict__ biasIn,
    u16* __restrict__ OutH, u16* __restrict__ OutL, const int z)
{
    // cells of 16B: Wh [0,512) Wl [512,1024) Xh [1024,1472) Xl [1472,1920)
    __shared__ u16 lds[1920 * 8];
    u16* Wh = lds;
    u16* Wl_ = lds + 512 * 8;
    u16* Xh = lds + 1024 * 8;
    u16* Xl = lds + 1472 * 8;

    const int t = threadIdx.x, w = t >> 6, ln = t & 63;
    const int lg = ln >> 4, l16 = ln & 15;
    const int ct = blockIdx.x & 1, mt = blockIdx.x >> 1;
    const int hb = blockIdx.y, h = hb >> 4, b = hb & 15;

    const u16* Ah = Ahi + ((size_t)(z ? b : hb) * NP + mt * 112) * CC;
    const u16* Al = Alo + ((size_t)(z ? b : hb) * NP + mt * 112) * CC;
    const u16* Bh = Whi + ((size_t)h * C8 + ct * 128) * CC;
    const u16* Bl = Wlo + ((size_t)h * C8 + ct * 128) * CC;
    const float scale = z ? (float)h : 1.0f;
    const float* bias = biasIn + h * C8;

    f32x4 acc[2][7];
    const f32x4 zf = {0.f, 0.f, 0.f, 0.f};
#pragma unroll
    for (int i = 0; i < 2; ++i)
#pragma unroll
        for (int j = 0; j < 7; ++j) acc[i][j] = zf;

    for (int k0 = 0; k0 < CC; k0 += 32) {
#pragma unroll
        for (int it = 0; it < 2; ++it) {
            int cell = it * 256 + t;
            int g = cell >> 7, o = cell & 127;
            cp16(Wh + (size_t)cell * 8, Bh + (size_t)o * CC + k0 + 8 * g);
            cp16(Wl_ + (size_t)cell * 8, Bl + (size_t)o * CC + k0 + 8 * g);
        }
        {
            int g = t / 112, n = t % 112;
            cp16(Xh + (size_t)t * 8, Ah + (size_t)n * CC + k0 + 8 * g);
            cp16(Xl + (size_t)t * 8, Al + (size_t)n * CC + k0 + 8 * g);
            if (t < 192) {
                int cell = 256 + t;
                int g2 = cell / 112, n2 = cell % 112;
                cp16(Xh + (size_t)cell * 8, Ah + (size_t)n2 * CC + k0 + 8 * g2);
                cp16(Xl + (size_t)cell * 8, Al + (size_t)n2 * CC + k0 + 8 * g2);
            }
        }
        __syncthreads();
        bf16x8 ah[2], al[2], bh[7], bl[7];
#pragma unroll
        for (int i = 0; i < 2; ++i) {
            ah[i] = *(const bf16x8*)(Wh + (size_t)(lg * 128 + w * 32 + i * 16 + l16) * 8);
            al[i] = *(const bf16x8*)(Wl_ + (size_t)(lg * 128 + w * 32 + i * 16 + l16) * 8);
        }
#pragma unroll
        for (int j = 0; j < 7; ++j) {
            bh[j] = *(const bf16x8*)(Xh + (size_t)(lg * 112 + j * 16 + l16) * 8);
            bl[j] = *(const bf16x8*)(Xl + (size_t)(lg * 112 + j * 16 + l16) * 8);
        }
#pragma unroll
        for (int i = 0; i < 2; ++i)
#pragma unroll
            for (int j = 0; j < 7; ++j)
                acc[i][j] = __builtin_amdgcn_mfma_f32_16x16x32_bf16(ah[i], bh[j], acc[i][j], 0, 0, 0);
#pragma unroll
        for (int i = 0; i < 2; ++i)
#pragma unroll
            for (int j = 0; j < 7; ++j)
                acc[i][j] = __builtin_amdgcn_mfma_f32_16x16x32_bf16(ah[i], bl[j], acc[i][j], 0, 0, 0);
#pragma unroll
        for (int i = 0; i < 2; ++i)
#pragma unroll
            for (int j = 0; j < 7; ++j)
                acc[i][j] = __builtin_amdgcn_mfma_f32_16x16x32_bf16(al[i], bh[j], acc[i][j], 0, 0, 0);
        __syncthreads();
    }

#pragma unroll
    for (int i = 0; i < 2; ++i) {
        int ob = ct * 128 + w * 32 + i * 16 + lg * 4;
#pragma unroll
        for (int j = 0; j < 7; ++j) {
            int n = mt * 112 + j * 16 + l16;
            u16x4 hv, lv;
#pragma unroll
            for (int r = 0; r < 4; ++r) {
                float v = scale * acc[i][j][r] + bias[ob + r];
                hv[r] = f2bf(v);
                lv[r] = f2bf(v - bf2f(hv[r]));
            }
            size_t of = ((size_t)hb * NP + n) * C8 + ob;
            *(u16x4*)(OutH + of) = hv;
            *(u16x4*)(OutL + of) = lv;
        }
    }
}

// ---------------------------------------------------------------- k_esm (MFMA)
// E = Q·K^T via split-bf16 MFMA; in-register row softmax.
// block = (mt: 64-row tile of m, hb); wave w: rows mt*64+w*16 .. +16, all 224 n.
__global__ __launch_bounds__(256, 2) void k_esm(
    const u16* __restrict__ Qh, const u16* __restrict__ Ql,
    const u16* __restrict__ Kh, const u16* __restrict__ Kl,
    float* __restrict__ alphas, u16* __restrict__ atnb)
{
    // cells of 16B: QH [0,256) QL [256,512) KH [512,1408) KL [1408,2304)
    __shared__ u16 lds[2304 * 8];
    u16* QHs = lds;
    u16* QLs = lds + 256 * 8;
    u16* KHs = lds + 512 * 8;
    u16* KLs = lds + 1408 * 8;

    const int t = threadIdx.x, w = t >> 6, ln = t & 63;
    const int lg = ln >> 4, l16 = ln & 15;
    const int mt = blockIdx.x, hb = blockIdx.y;
    const int h = hb >> 4, b = hb & 15;
    const size_t base = (size_t)hb * NP * C8;

    f32x4 e[14];
    const f32x4 zf = {0.f, 0.f, 0.f, 0.f};
#pragma unroll
    for (int j = 0; j < 14; ++j) e[j] = zf;

    for (int o0 = 0; o0 < C8; o0 += 32) {
        {   // stage Q tile: 64 rows (mt*64.., may over-read pad area: finite, discarded)
            int g = t >> 6, mr = t & 63;
            size_t src = base + (size_t)(mt * 64 + mr) * C8 + o0 + 8 * g;
            cp16(QHs + (size_t)t * 8, Qh + src);
            cp16(QLs + (size_t)t * 8, Ql + src);
        }
#pragma unroll
        for (int it = 0; it < 4; ++it) {   // stage K tile: 224 rows
            int cell = it * 256 + t;
            if (cell < 896) {
                int g = cell / 224, n = cell % 224;
                size_t src = base + (size_t)n * C8 + o0 + 8 * g;
                cp16(KHs + (size_t)cell * 8, Kh + src);
                cp16(KLs + (size_t)cell * 8, Kl + src);
            }
        }
        __syncthreads();
        bf16x8 ah = *(const bf16x8*)(QHs + (size_t)(lg * 64 + w * 16 + l16) * 8);
        bf16x8 al = *(const bf16x8*)(QLs + (size_t)(lg * 64 + w * 16 + l16) * 8);
#pragma unroll
        for (int j = 0; j < 14; ++j) {
            bf16x8 bh = *(const bf16x8*)(KHs + (size_t)(lg * 224 + j * 16 + l16) * 8);
            bf16x8 bl = *(const bf16x8*)(KLs + (size_t)(lg * 224 + j * 16 + l16) * 8);
            e[j] = __builtin_amdgcn_mfma_f32_16x16x32_bf16(ah, bh, e[j], 0, 0, 0);
            e[j] = __builtin_amdgcn_mfma_f32_16x16x32_bf16(ah, bl, e[j], 0, 0, 0);
            e[j] = __builtin_amdgcn_mfma_f32_16x16x32_bf16(al, bh, e[j], 0, 0, 0);
        }
        __syncthreads();
    }

    // softmax: thread holds rows m = mt*64 + w*16 + lg*4 + r (r<4), cols n = j*16 + l16
#pragma unroll
    for (int r = 0; r < 4; ++r) {
        float mx = -1e30f;
#pragma unroll
        for (int j = 0; j < 14; ++j) {
            int n = j * 16 + l16;
            if (n < NN) mx = fmaxf(mx, e[j][r]);
        }
#pragma unroll
        for (int off = 1; off <= 8; off <<= 1) mx = fmaxf(mx, __shfl_xor(mx, off));
        float p[14];
        float s = 0.f;
#pragma unroll
        for (int j = 0; j < 14; ++j) {
            int n = j * 16 + l16;
            if (n < NN) { p[j] = __expf(e[j][r] - mx); s += p[j]; }
            else p[j] = 0.f;
        }
#pragma unroll
        for (int off = 1; off <= 8; off <<= 1) s += __shfl_xor(s, off);
        const float inv = 1.0f / s;
        const int m = mt * 64 + w * 16 + lg * 4 + r;
        if (m < NP) {
            u16* arow = atnb + ((size_t)hb * NP + m) * NP;
#pragma unroll
            for (int j = 0; j < 14; ++j) {
                int n = j * 16 + l16;
                float a = p[j] * inv;
                arow[n] = f2bf(a);
                if (m < NN && n < NN)
                    alphas[(((size_t)b * NN + m) * NN + n) * HH + h] = a;
            }
        }
    }
}

// ---------------------------------------------------------------- k_vpv (MFMA)
__global__ __launch_bounds__(256, 2) void k_vpv(
    const u16* __restrict__ Wvb,   // [h][2048][2048]
    const u16* __restrict__ xhi,   // [h][b][224][2048]
    const u16* __restrict__ atnb,  // [h][b][224][224]
    const float* __restrict__ bv,
    const float* __restrict__ gamma,
    u16* __restrict__ outs)        // [h][b][2048][196]
{
    __shared__ u16 lds[4992 * 8];
    u16* Aw = lds;
    u16* Bx = lds + 512 * 8;
    u16* Vb = lds + 1408 * 8;

    const int t = threadIdx.x, w = t >> 6, ln = t & 63;
    const int lg = ln >> 4, l16 = ln & 15;
    const int wr = w >> 1, wc = w & 1;
    const int ct = blockIdx.x, h = blockIdx.y >> 4, b = blockIdx.y & 15;
    const size_t wv_base = ((size_t)h * CC + ct * 128) * CC;
    const size_t xh_base = (size_t)(h * BB + b) * NP * CC;
    const size_t p_base  = (size_t)(h * BB + b) * NP * NP;

    f32x4 acc[4][7];
    const f32x4 zf = {0.f, 0.f, 0.f, 0.f};
#pragma unroll
    for (int i = 0; i < 4; ++i)
#pragma unroll
        for (int j = 0; j < 7; ++j) acc[i][j] = zf;

    // phase 1: V = Wv @ x
    for (int k0 = 0; k0 < CC; k0 += 32) {
#pragma unroll
        for (int it = 0; it < 2; ++it) {
            int cell = it * 256 + w * 64 + ln;
            int g = cell >> 7, o = cell & 127;
            cp16(Aw + (size_t)cell * 8, Wvb + wv_base + (size_t)o * CC + k0 + 8 * g);
        }
#pragma unroll
        for (int it = 0; it < 4; ++it) {
            if (it < 3 || w < 2) {
                int cell = it * 256 + w * 64 + ln;
                int g = cell / NP, n = cell % NP;
                cp16(Bx + (size_t)cell * 8, xhi + xh_base + (size_t)n * CC + k0 + 8 * g);
            }
        }
        __syncthreads();
        bf16x8 a[4], bq[7];
#pragma unroll
        for (int i = 0; i < 4; ++i)
            a[i] = *(const bf16x8*)(Aw + (size_t)(lg * 128 + wr * 64 + i * 16 + l16) * 8);
#pragma unroll
        for (int j = 0; j < 7; ++j)
            bq[j] = *(const bf16x8*)(Bx + (size_t)(lg * NP + wc * 112 + j * 16 + l16) * 8);
#pragma unroll
        for (int i = 0; i < 4; ++i)
#pragma unroll
            for (int j = 0; j < 7; ++j)
                acc[i][j] = __builtin_amdgcn_mfma_f32_16x16x32_bf16(a[i], bq[j], acc[i][j], 0, 0, 0);
        __syncthreads();
    }

    // park V (+bias) in LDS
#pragma unroll
    for (int i = 0; i < 4; ++i) {
        int cb = wr * 64 + i * 16 + lg * 4;
#pragma unroll
        for (int j = 0; j < 7; ++j) {
            int n = wc * 112 + j * 16 + l16;
#pragma unroll
            for (int r = 0; r < 4; ++r) {
                float v = acc[i][j][r] + bv[h * CC + ct * 128 + cb + r];
                Vb[(size_t)((n >> 3) * 128 + cb + r) * 8 + (n & 7)] = f2bf(v);
            }
        }
    }
    __syncthreads();

    // phase 2: out = V @ P^T
#pragma unroll
    for (int i = 0; i < 4; ++i)
#pragma unroll
        for (int j = 0; j < 7; ++j) acc[i][j] = zf;

    for (int s = 0; s < 7; ++s) {
#pragma unroll
        for (int it = 0; it < 4; ++it) {
            if (it < 3 || w < 2) {
                int cell = it * 256 + w * 64 + ln;
                int g = cell / NP, m = cell % NP;
                cp16(Bx + (size_t)cell * 8, atnb + p_base + (size_t)m * NP + s * 32 + 8 * g);
            }
        }
        __syncthreads();
        bf16x8 a[4], bq[7];
#pragma unroll
        for (int i = 0; i < 4; ++i)
            a[i] = *(const bf16x8*)(Vb + (size_t)((4 * s + lg) * 128 + wr * 64 + i * 16 + l16) * 8);
#pragma unroll
        for (int j = 0; j < 7; ++j)
            bq[j] = *(const bf16x8*)(Bx + (size_t)(lg * NP + wc * 112 + j * 16 + l16) * 8);
#pragma unroll
        for (int i = 0; i < 4; ++i)
#pragma unroll
            for (int j = 0; j < 7; ++j)
                acc[i][j] = __builtin_amdgcn_mfma_f32_16x16x32_bf16(a[i], bq[j], acc[i][j], 0, 0, 0);
        __syncthreads();
    }

    // epilogue
    const float gm = gamma[h];
    const size_t ob = ((size_t)(h * BB + b) * CC + ct * 128) * NN;
#pragma unroll
    for (int i = 0; i < 4; ++i) {
        int cb = wr * 64 + i * 16 + lg * 4;
#pragma unroll
        for (int j = 0; j < 7; ++j) {
            int m = wc * 112 + j * 16 + l16;
            if (m < NN) {
                const u16* xp = xhi + xh_base + (size_t)m * CC + ct * 128 + cb;
#pragma unroll
                for (int r = 0; r < 4; ++r) {
                    float ov = gm * acc[i][j][r] + bf2f(xp[r]);
                    outs[ob + (size_t)(cb + r) * NN + m] = f2bf(ov);
                }
            }
        }
    }
}

// ---------------------------------------------------------------- k_lin (MFMA, split-K)
__global__ __launch_bounds__(256, 2) void k_lin(
    const u16* __restrict__ feats, const float* __restrict__ Wl,
    float* __restrict__ part)
{
    __shared__ u16 lds[(256 + 260) * 8];
    u16* Aa = lds;
    u16* Bb = lds + 256 * 8;
    const int t = threadIdx.x, w = t >> 6, ln = t & 63;
    const int lg = ln >> 4, l16 = ln & 15;
    const int wr = w >> 1, wc = w & 1;
    const int dmt = blockIdx.x, ch = blockIdx.y;
    const int ga = t >> 6, aa = t & 63;
    const u16* asrc = feats + (size_t)((aa & 3) * BB + (aa >> 2)) * FF + (size_t)ch * 6272 + 8 * ga;
    const int dmB = t >> 2, gB = t & 3;
    const float* bsrc = Wl + ((size_t)dmt * 64 + dmB) * FF + (size_t)ch * 6272 + 8 * gB;

    f32x4 acc[2][2];
    const f32x4 zf = {0.f, 0.f, 0.f, 0.f};
    acc[0][0] = zf; acc[0][1] = zf; acc[1][0] = zf; acc[1][1] = zf;

    for (int k0 = 0; k0 < 6272; k0 += 32) {
        cp16(Aa + (size_t)t * 8, asrc + k0);
        float4 f0 = *(const float4*)(bsrc + k0);
        float4 f1 = *(const float4*)(bsrc + k0 + 4);
        u16x8 bb;
        bb.s0 = f2bf(f0.x); bb.s1 = f2bf(f0.y); bb.s2 = f2bf(f0.z); bb.s3 = f2bf(f0.w);
        bb.s4 = f2bf(f1.x); bb.s5 = f2bf(f1.y); bb.s6 = f2bf(f1.z); bb.s7 = f2bf(f1.w);
        *(u16x8*)(Bb + (size_t)(gB * 65 + dmB) * 8) = bb;
        __syncthreads();
        bf16x8 a[2], bq[2];
#pragma unroll
        for (int i = 0; i < 2; ++i)
            a[i] = *(const bf16x8*)(Aa + (size_t)(lg * 64 + wr * 32 + i * 16 + l16) * 8);
#pragma unroll
        for (int j = 0; j < 2; ++j)
            bq[j] = *(const bf16x8*)(Bb + (size_t)(lg * 65 + wc * 32 + j * 16 + l16) * 8);
#pragma unroll
        for (int i = 0; i < 2; ++i)
#pragma unroll
            for (int j = 0; j < 2; ++j)
                acc[i][j] = __builtin_amdgcn_mfma_f32_16x16x32_bf16(a[i], bq[j], acc[i][j], 0, 0, 0);
        __syncthreads();
    }
#pragma unroll
    for (int i = 0; i < 2; ++i)
#pragma unroll
        for (int j = 0; j < 2; ++j)
#pragma unroll
            for (int r = 0; r < 4; ++r)
                part[((size_t)ch * 64 + wr * 32 + i * 16 + lg * 4 + r) * DM
                     + dmt * 64 + wc * 32 + j * 16 + l16] = acc[i][j][r];
}

// ---------------------------------------------------------------- k_red
__global__ __launch_bounds__(256) void k_red(const float* __restrict__ part,
                                             const float* __restrict__ bl,
                                             float* __restrict__ out0)
{
    int gid = blockIdx.x * 256 + threadIdx.x;
    if (gid < 64 * DM) {
        int dm = gid & (DM - 1);
        float s = bl[dm];
        for (int c2 = 0; c2 < 64; ++c2) s += part[(size_t)c2 * 64 * DM + gid];
        out0[gid] = s;
    }
}

// ---------------------------------------------------------------- launch
extern "C" void kernel_launch(void* const* d_in, const int* in_sizes, int n_in,
                              void* d_out, int out_size, void* d_ws, size_t ws_size,
                              hipStream_t stream)
{
    const float* bef   = (const float*)d_in[0];
    const float* aft   = (const float*)d_in[1];
    const float* Wq    = (const float*)d_in[2];
    const float* bq    = (const float*)d_in[3];
    const float* Wk    = (const float*)d_in[4];
    const float* bk    = (const float*)d_in[5];
    const float* Wv    = (const float*)d_in[6];
    const float* bv    = (const float*)d_in[7];
    const float* gamma = (const float*)d_in[8];
    const float* Wl    = (const float*)d_in[9];
    const float* bl    = (const float*)d_in[10];

    float* out0   = (float*)d_out;
    float* alphas = out0 + (size_t)BB * HH * DM;

    float* ws = (float*)d_ws;
    // flat layout, no aliasing (ws is ~3.3 GB; we use ~293 MB)
    u16* xhi  = (u16*)ws;                        // 14,680,064 f32
    u16* xlo  = (u16*)(ws + 14680064);           // 14,680,064
    u16* dhi  = (u16*)(ws + 29360128);           //  3,670,016
    u16* dlo  = (u16*)(ws + 33030144);           //  3,670,016
    u16* wqh  = (u16*)(ws + 36700160);           //  1,048,576
    u16* wql  = (u16*)(ws + 37748736);
    u16* wkh  = (u16*)(ws + 38797312);
    u16* wkl  = (u16*)(ws + 39845888);
    u16* Qhb  = (u16*)(ws + 40894464);           //  1,835,008 each (Q/K hi/lo)
    u16* Qlb  = (u16*)(ws + 42729472);
    u16* Khb  = (u16*)(ws + 44564480);
    u16* Klb  = (u16*)(ws + 46399488);
    u16* Wvb  = (u16*)(ws + 48234496);           //  8,388,608
    u16* atnb = (u16*)(ws + 56623104);           //  1,605,632
    u16* outs = (u16*)(ws + 58228736);           // 12,845,056
    float* part = ws + 71073792;                 //  2,097,152 -> end 73,170,944 (292.7 MB)

    k_prep<<<2048, 256, 0, stream>>>(bef, aft, xhi, xlo, dhi, dlo);
    k_castQK<<<1024, 256, 0, stream>>>(Wq, Wk, wqh, wql, wkh, wkl);
    k_qkm<<<dim3(4, 64), 256, 0, stream>>>(xhi, xlo, wqh, wql, bq, Qhb, Qlb, 0);
    k_qkm<<<dim3(4, 64), 256, 0, stream>>>(dhi, dlo, wkh, wkl, bk, Khb, Klb, 1);
    k_castWv<<<2048, 256, 0, stream>>>(Wv, Wvb);
    k_esm<<<dim3(4, 64), 256, 0, stream>>>(Qhb, Qlb, Khb, Klb, alphas, atnb);
    k_vpv<<<dim3(16, 64), 256, 0, stream>>>(Wvb, xhi, atnb, bv, gamma, outs);
    k_lin<<<dim3(8, 64), 256, 0, stream>>>(outs, Wl, part);
    k_red<<<128, 256, 0, stream>>>(part, bl, out0);
}